// Round 1
// baseline (333.952 us; speedup 1.0000x reference)
//
#include <hip/hip_runtime.h>

// NonLocalAttentionStack on MI355X.
// Dims: B=1, T=4, C=128, H=W=96, NHEADS=4 (c=32/head), WS=7 (49 cands), PS=3, K=16.
// Pipeline: prep -> LN+QKV (fp32 GEMM) -> search+topk+softmax (fp32) ->
//           stack build (bf16) -> implicit-conv MFMA GEMM (bf16 in, fp32 accum).

typedef float  f32x4  __attribute__((ext_vector_type(4)));
typedef __bf16 bf16x8 __attribute__((ext_vector_type(8)));

// ---------------------------------------------------------------------------
// prep: Wt[c][o=384] = {wq|wk|wv}[o][c];  pwt[g][kd][d=9][o=32][i=32] bf16
// ---------------------------------------------------------------------------
__global__ __launch_bounds__(256) void prep_kernel(
    const float* __restrict__ wq, const float* __restrict__ wk, const float* __restrict__ wv,
    const float* __restrict__ pw, float* __restrict__ Wt, __bf16* __restrict__ pwt) {
  int idx = blockIdx.x * 256 + threadIdx.x;
  const int NPW = 4 * 16 * 9 * 32 * 32;  // 589824
  if (idx < NPW) {
    int i  = idx & 31;
    int ol = (idx >> 5) & 31;
    int d  = (idx >> 10) % 9;
    int r  = (idx >> 10) / 9;   // g*16+kd
    int kd = r & 15;
    int g  = r >> 4;
    int o  = g * 32 + ol;
    // proj_w layout (O=128, I=32, KD=16, 3, 3); d = kh*3+kw
    pwt[idx] = (__bf16)pw[((o * 32 + i) * 16 + kd) * 9 + d];
  } else {
    int widx = idx - NPW;
    if (widx < 128 * 384) {
      int o = widx % 384;
      int c = widx / 384;
      const float* __restrict__ src = (o < 128) ? wq : (o < 256 ? wk : wv);
      Wt[widx] = src[(o & 127) * 128 + c];
    }
  }
}

// ---------------------------------------------------------------------------
// LN + QKV GEMM.  M-tile=128 pixels, N-tile=64 outputs, K staged in 2x64.
// Output layout q/k/v: [t*4+head][pix][c32] fp32 (c contiguous).
// grid (6, 288), 128 threads.
// ---------------------------------------------------------------------------
__global__ __launch_bounds__(128) void qkv_kernel(
    const float* __restrict__ vid, const float* __restrict__ lnw, const float* __restrict__ lnb,
    const float* __restrict__ Wt, const float* __restrict__ bq, const float* __restrict__ bk,
    const float* __restrict__ bv, float* __restrict__ qb, float* __restrict__ kb,
    float* __restrict__ vb) {
  __shared__ __align__(16) float Xt[64][128];   // [k-chunk][pixel]
  __shared__ __align__(16) float Wl[64][64];    // [k-chunk][out]
  __shared__ float muS[128], rsS[128], lwS[128], lbS[128];
  int tid = threadIdx.x;
  int mt = blockIdx.y;
  int N0 = blockIdx.x * 64;
  int f  = mt / 72;
  int pf = (mt % 72) * 128;

  // LN stats: one pixel per thread (coalesced strided reads over c)
  {
    const float* __restrict__ vp = vid + (size_t)f * 128 * 9216 + pf + tid;
    float s = 0.f, s2 = 0.f;
    #pragma unroll 4
    for (int c = 0; c < 128; ++c) { float x = vp[(size_t)c * 9216]; s += x; s2 += x * x; }
    float m_ = s * (1.f / 128.f);
    float v_ = fmaxf(s2 * (1.f / 128.f) - m_ * m_, 0.f);
    muS[tid] = m_;
    rsS[tid] = rsqrtf(v_ + 1e-6f);
    lwS[tid] = lnw[tid];
    lbS[tid] = lnb[tid];
  }
  __syncthreads();

  int tx = tid & 7, ty = tid >> 3;
  int m0 = ty * 8, n0 = tx * 8;
  float acc[8][8];
  #pragma unroll
  for (int a = 0; a < 8; ++a)
    #pragma unroll
    for (int b = 0; b < 8; ++b) acc[a][b] = 0.f;

  for (int kc = 0; kc < 2; ++kc) {
    __syncthreads();
    for (int i = tid; i < 64 * 128; i += 128) {
      int kk = i >> 7, m = i & 127;
      int c = kc * 64 + kk;
      float x = vid[((size_t)f * 128 + c) * 9216 + pf + m];
      Xt[kk][m] = (x - muS[m]) * rsS[m] * lwS[c] + lbS[c];
    }
    for (int i = tid; i < 64 * 64; i += 128) {
      int kk = i >> 6, n = i & 63;
      Wl[kk][n] = Wt[(size_t)(kc * 64 + kk) * 384 + N0 + n];
    }
    __syncthreads();
    #pragma unroll 2
    for (int kk = 0; kk < 64; ++kk) {
      float xa[8], wa[8];
      *(float4*)&xa[0] = *(const float4*)&Xt[kk][m0];
      *(float4*)&xa[4] = *(const float4*)&Xt[kk][m0 + 4];
      *(float4*)&wa[0] = *(const float4*)&Wl[kk][n0];
      *(float4*)&wa[4] = *(const float4*)&Wl[kk][n0 + 4];
      #pragma unroll
      for (int a = 0; a < 8; ++a)
        #pragma unroll
        for (int b = 0; b < 8; ++b)
          acc[a][b] = fmaf(xa[a], wa[b], acc[a][b]);
    }
  }

  // epilogue: o0..o0+7 stay within one tensor, one head, contiguous c
  int o0 = N0 + n0;
  int sel = o0 >> 7;
  const float* __restrict__ bias = (sel == 0) ? bq : (sel == 1 ? bk : bv);
  float* __restrict__ dst = (sel == 0) ? qb : (sel == 1 ? kb : vb);
  int oc = o0 & 127;
  int head = oc >> 5;
  int c0 = oc & 31;
  float bsv[8];
  #pragma unroll
  for (int b = 0; b < 8; ++b) bsv[b] = bias[oc + b];
  size_t obase = (size_t)(f * 4 + head) * 9216 * 32;
  #pragma unroll
  for (int a = 0; a < 8; ++a) {
    size_t pbase = obase + (size_t)(pf + m0 + a) * 32 + c0;
    *(float4*)&dst[pbase] =
        make_float4(acc[a][0] + bsv[0], acc[a][1] + bsv[1], acc[a][2] + bsv[2], acc[a][3] + bsv[3]);
    *(float4*)&dst[pbase + 4] =
        make_float4(acc[a][4] + bsv[4], acc[a][5] + bsv[5], acc[a][6] + bsv[6], acc[a][7] + bsv[7]);
  }
}

// ---------------------------------------------------------------------------
// search + topk + softmax.  12x12 pixel tile per block, one (t,head).
// s-region 14x14 (box-sum halo), k-region 20x20 staged in LDS (pad 32->36).
// grid (64, 16), 256 threads (196 active for s/topk).
// ---------------------------------------------------------------------------
__global__ __launch_bounds__(256) void search_kernel(
    const float* __restrict__ qb, const float* __restrict__ kb,
    float* __restrict__ wgtb, int* __restrict__ indb) {
  __shared__ __align__(16) float klds[400 * 36];
  __shared__ float slds[196];
  int tid = threadIdx.x;
  int th = blockIdx.y;
  int tile = blockIdx.x;
  int ty0 = (tile >> 3) * 12, tx0 = (tile & 7) * 12;
  const float* __restrict__ kbase = kb + (size_t)th * 9216 * 32;

  for (int i = tid; i < 400 * 8; i += 256) {
    int pix = i >> 3, c4 = i & 7;
    int ry = pix / 20, rx = pix % 20;
    int gy = ty0 - 4 + ry, gx = tx0 - 4 + rx;
    float4 val = make_float4(0.f, 0.f, 0.f, 0.f);
    if ((unsigned)gy < 96u && (unsigned)gx < 96u)
      val = *(const float4*)&kbase[(size_t)(gy * 96 + gx) * 32 + c4 * 4];
    *(float4*)&klds[pix * 36 + c4 * 4] = val;
  }

  int sy = tid / 14, sx = tid % 14;
  bool active = tid < 196;
  int gy = ty0 - 1 + sy, gx = tx0 - 1 + sx;
  bool qok = active && (unsigned)gy < 96u && (unsigned)gx < 96u;
  float4 qv[8];
  #pragma unroll
  for (int j = 0; j < 8; ++j) qv[j] = make_float4(0.f, 0.f, 0.f, 0.f);
  if (qok) {
    const float* __restrict__ qp = qb + ((size_t)th * 9216 + gy * 96 + gx) * 32;
    #pragma unroll
    for (int j = 0; j < 8; ++j) qv[j] = *(const float4*)&qp[j * 4];
  }
  bool inner = active && sy >= 1 && sy <= 12 && sx >= 1 && sx <= 12;
  int py = ty0 + sy - 1, px = tx0 + sx - 1;

  float tv[16]; int tix[16];
  #pragma unroll
  for (int j = 0; j < 16; ++j) { tv[j] = -3.0e38f; tix[j] = 0; }
  __syncthreads();

  for (int oi = 0; oi < 49; ++oi) {
    int dy = oi / 7, dx = oi % 7;
    if (active) {
      const float* __restrict__ kp = &klds[((sy + dy) * 20 + (sx + dx)) * 36];
      float sdot = 0.f;
      #pragma unroll
      for (int j = 0; j < 8; ++j) {
        float4 kv = *(const float4*)&kp[j * 4];
        sdot += qv[j].x * kv.x + qv[j].y * kv.y + qv[j].z * kv.z + qv[j].w * kv.w;
      }
      slds[tid] = sdot;
    }
    __syncthreads();
    if (inner) {
      float sc = 0.f;
      #pragma unroll
      for (int a = 0; a < 3; ++a)
        #pragma unroll
        for (int b = 0; b < 3; ++b)
          sc += slds[(sy - 1 + a) * 14 + (sx - 1 + b)];
      // streaming insertion, jax.lax.top_k semantics (desc, ties -> lower index)
      float cv = sc; int ci = oi; bool ins = false;
      #pragma unroll
      for (int j = 0; j < 16; ++j) {
        bool sw = ins || (cv > tv[j]);
        float pv = tv[j]; int pi = tix[j];
        tv[j]  = sw ? cv : pv;
        tix[j] = sw ? ci : pi;
        cv = sw ? pv : cv;
        ci = sw ? pi : ci;
        ins = sw;
      }
    }
    __syncthreads();
  }

  if (inner) {
    float mx = tv[0];
    float e[16], ssum = 0.f;
    #pragma unroll
    for (int j = 0; j < 16; ++j) { e[j] = __expf(tv[j] - mx); ssum += e[j]; }
    float inv = 1.f / ssum;
    size_t base = ((size_t)th * 9216 + py * 96 + px) * 16;
    #pragma unroll
    for (int j = 0; j < 4; ++j) {
      *(float4*)&wgtb[base + j * 4] =
          make_float4(e[j*4] * inv, e[j*4+1] * inv, e[j*4+2] * inv, e[j*4+3] * inv);
      *(int4*)&indb[base + j * 4] = make_int4(tix[j*4], tix[j*4+1], tix[j*4+2], tix[j*4+3]);
    }
  }
}

// ---------------------------------------------------------------------------
// stack build: A[fg][pix][kd][i32] bf16 = wgt * v[nbr];  4 threads per (pix,kd)
// ---------------------------------------------------------------------------
__global__ __launch_bounds__(256) void abuild_kernel(
    const float* __restrict__ vb, const float* __restrict__ wgtb, const int* __restrict__ indb,
    __bf16* __restrict__ Ab, int fbase) {
  int gid = blockIdx.x * 64 + (threadIdx.x >> 2);
  int sub = threadIdx.x & 3;
  int kd  = gid & 15;
  int rest = gid >> 4;
  int pix = rest % 9216;
  int fg  = rest / 9216;           // f_local*4+g
  int th  = fbase * 4 + fg;        // == (fbase+f_local)*4+g
  size_t qidx = ((size_t)th * 9216 + pix) * 16 + kd;
  int ind = indb[qidx];
  float wgt = wgtb[qidx];
  int ny = pix / 96 + ind / 7 - 3;
  int nx = pix % 96 + ind % 7 - 3;
  float vals[8] = {0.f, 0.f, 0.f, 0.f, 0.f, 0.f, 0.f, 0.f};
  if ((unsigned)ny < 96u && (unsigned)nx < 96u) {
    const float* __restrict__ vp = &vb[((size_t)th * 9216 + ny * 96 + nx) * 32 + sub * 8];
    *(float4*)&vals[0] = *(const float4*)&vp[0];
    *(float4*)&vals[4] = *(const float4*)&vp[4];
  }
  bf16x8 ov;
  #pragma unroll
  for (int j = 0; j < 8; ++j) ov[j] = (__bf16)(vals[j] * wgt);
  *(bf16x8*)&Ab[(((size_t)fg * 9216 + pix) * 16 + kd) * 32 + sub * 8] = ov;
}

// ---------------------------------------------------------------------------
// implicit-conv GEMM: out[o,h,w] = sum_{d,kd,i} A[p+delta(d)][kd][i]*pw[o,i,kd,d] + b
// 16x16 pixel tile, 18x18 A halo in LDS (row pad 32->40 bf16), 4 waves.
// Each wave: 4 image rows x 32 outs via mfma_f32_16x16x32_bf16.
// grid (36, nf*4), 256 threads.
// ---------------------------------------------------------------------------
__global__ __launch_bounds__(256) void proj_kernel(
    const __bf16* __restrict__ Ab, const __bf16* __restrict__ pwt,
    const float* __restrict__ pb, float* __restrict__ outp, int fbase) {
  __shared__ __align__(16) __bf16 Alds[324 * 40];
  __shared__ __align__(16) __bf16 Blds[288 * 40];
  int tid = threadIdx.x;
  int fg = blockIdx.y;
  int g = fg & 3, fl = fg >> 2;
  int tile = blockIdx.x;
  int ty0 = (tile / 6) * 16, tx0 = (tile % 6) * 16;
  int lane = tid & 63, wid = tid >> 6;
  int kg = lane >> 4, lr = lane & 15;

  f32x4 acc[4][2];
  #pragma unroll
  for (int a = 0; a < 4; ++a) {
    acc[a][0] = (f32x4)(0.0f);
    acc[a][1] = (f32x4)(0.0f);
  }

  for (int kd = 0; kd < 16; ++kd) {
    __syncthreads();
    // stage A halo region (18x18 pixels x 32 ch) for this kd
    for (int i = tid; i < 1296; i += 256) {
      int pix = i >> 2, c = i & 3;
      int ry = pix / 18, rx = pix % 18;
      int gy2 = ty0 - 1 + ry, gx2 = tx0 - 1 + rx;
      int4 val = make_int4(0, 0, 0, 0);
      if ((unsigned)gy2 < 96u && (unsigned)gx2 < 96u)
        val = *(const int4*)&Ab[(((size_t)fg * 9216 + gy2 * 96 + gx2) * 16 + kd) * 32 + c * 8];
      *(int4*)&Alds[pix * 40 + c * 8] = val;
    }
    // stage B: 9 taps x 32 outs x 32 ch for this (g,kd)
    {
      const __bf16* __restrict__ bsrc = pwt + (size_t)(g * 16 + kd) * 9216;
      for (int i = tid; i < 1152; i += 256) {
        int row = i >> 2, c = i & 3;
        *(int4*)&Blds[row * 40 + c * 8] = *(const int4*)&bsrc[row * 32 + c * 8];
      }
    }
    __syncthreads();
    #pragma unroll
    for (int d = 0; d < 9; ++d) {
      int dy = d / 3 - 1, dx = d % 3 - 1;
      bf16x8 b0 = *(const bf16x8*)&Blds[(d * 32 + lr) * 40 + kg * 8];
      bf16x8 b1 = *(const bf16x8*)&Blds[(d * 32 + 16 + lr) * 40 + kg * 8];
      #pragma unroll
      for (int mt = 0; mt < 4; ++mt) {
        int ry = wid * 4 + mt + 1 + dy;
        int rx = lr + 1 + dx;
        bf16x8 af = *(const bf16x8*)&Alds[(ry * 18 + rx) * 40 + kg * 8];
        acc[mt][0] = __builtin_amdgcn_mfma_f32_16x16x32_bf16(af, b0, acc[mt][0], 0, 0, 0);
        acc[mt][1] = __builtin_amdgcn_mfma_f32_16x16x32_bf16(af, b1, acc[mt][1], 0, 0, 0);
      }
    }
  }

  // epilogue: D col = lane&15 -> o, D row = kg*4+j -> pixel x
  int x0 = tx0 + kg * 4;
  int tglob = fbase + fl;
  #pragma unroll
  for (int mt = 0; mt < 4; ++mt) {
    int y = ty0 + wid * 4 + mt;
    #pragma unroll
    for (int nt = 0; nt < 2; ++nt) {
      int o = g * 32 + nt * 16 + lr;
      float bias = pb[o];
      float4 res = make_float4(acc[mt][nt][0] + bias, acc[mt][nt][1] + bias,
                               acc[mt][nt][2] + bias, acc[mt][nt][3] + bias);
      *(float4*)&outp[(size_t)(tglob * 128 + o) * 9216 + y * 96 + x0] = res;
    }
  }
}

// ---------------------------------------------------------------------------
extern "C" void kernel_launch(void* const* d_in, const int* in_sizes, int n_in,
                              void* d_out, int out_size, void* d_ws, size_t ws_size,
                              hipStream_t stream) {
  const float* vid = (const float*)d_in[0];
  const float* lnw = (const float*)d_in[1];
  const float* lnb = (const float*)d_in[2];
  const float* wq  = (const float*)d_in[3];
  const float* bq  = (const float*)d_in[4];
  const float* wk  = (const float*)d_in[5];
  const float* bk  = (const float*)d_in[6];
  const float* wv_ = (const float*)d_in[7];
  const float* bv  = (const float*)d_in[8];
  const float* pw  = (const float*)d_in[9];
  const float* pb  = (const float*)d_in[10];
  float* outp = (float*)d_out;

  const size_t SZ_T  = (size_t)16 * 9216 * 32 * 4;   // q/k/v each: 18,874,368 B
  const size_t SZ_W  = (size_t)16 * 9216 * 16 * 4;   // wgt / ind:  9,437,184 B
  const size_t SZ_A1 = (size_t)4 * 9216 * 16 * 32 * 2; // stack per frame: 37,748,736 B
  const size_t SZ_WT = 128 * 384 * 4;
  const size_t SZ_PW = (size_t)4 * 16 * 9 * 32 * 32 * 2;
  const size_t fixed = SZ_T + 2 * SZ_W + SZ_WT + SZ_PW;

  int nf = 4;  // frames per stack chunk (shrink if workspace is small)
  while (nf > 1 && (size_t)nf * SZ_A1 + fixed > ws_size) nf >>= 1;

  char* base = (char*)d_ws;
  __bf16* Ab = (__bf16*)base;                 // stack chunk (overlays q,k)
  float* qb = (float*)base;                   // q overlays stack region
  float* kb = (float*)(base + SZ_T);          // k overlays stack region
  char* p = base + (size_t)nf * SZ_A1;
  float* vb = (float*)p;        p += SZ_T;
  float* wgtb = (float*)p;      p += SZ_W;
  int*   indb = (int*)p;        p += SZ_W;
  float* Wt = (float*)p;        p += SZ_WT;
  __bf16* pwt = (__bf16*)p;

  prep_kernel<<<2496, 256, 0, stream>>>(wq, wk, wv_, pw, Wt, pwt);
  qkv_kernel<<<dim3(6, 288), 128, 0, stream>>>(vid, lnw, lnb, Wt, bq, bk, bv, qb, kb, vb);
  search_kernel<<<dim3(64, 16), 256, 0, stream>>>(qb, kb, wgtb, indb);
  for (int fb = 0; fb < 4; fb += nf) {
    abuild_kernel<<<nf * 9216, 256, 0, stream>>>(vb, wgtb, indb, Ab, fb);
    proj_kernel<<<dim3(36, nf * 4), 256, 0, stream>>>(Ab, pwt, pb, outp, fb);
  }
}

// Round 2
// 311.504 us; speedup vs baseline: 1.0721x; 1.0721x over previous
//
#include <hip/hip_runtime.h>

// NonLocalAttentionStack on MI355X.
// Dims: B=1, T=4, C=128, H=W=96, NHEADS=4 (c=32/head), WS=7 (49 cands), PS=3, K=16.
// Pipeline: prep -> ln_stats -> QKV (fp32 GEMM) -> search+topk+softmax (fp32) ->
//           stack build (bf16) -> implicit-conv MFMA GEMM (bf16 in, fp32 accum).

typedef float  f32x4  __attribute__((ext_vector_type(4)));
typedef __bf16 bf16x8 __attribute__((ext_vector_type(8)));

// ---------------------------------------------------------------------------
// prep: Wt[c][o=384] = {wq|wk|wv}[o][c];  pwt[g][kd][d=9][o=32][i=32] bf16
// ---------------------------------------------------------------------------
__global__ __launch_bounds__(256) void prep_kernel(
    const float* __restrict__ wq, const float* __restrict__ wk, const float* __restrict__ wv,
    const float* __restrict__ pw, float* __restrict__ Wt, __bf16* __restrict__ pwt) {
  int idx = blockIdx.x * 256 + threadIdx.x;
  const int NPW = 4 * 16 * 9 * 32 * 32;  // 589824
  if (idx < NPW) {
    int i  = idx & 31;
    int ol = (idx >> 5) & 31;
    int d  = (idx >> 10) % 9;
    int r  = (idx >> 10) / 9;   // g*16+kd
    int kd = r & 15;
    int g  = r >> 4;
    int o  = g * 32 + ol;
    pwt[idx] = (__bf16)pw[((o * 32 + i) * 16 + kd) * 9 + d];
  } else {
    int widx = idx - NPW;
    if (widx < 128 * 384) {
      int o = widx % 384;
      int c = widx / 384;
      const float* __restrict__ src = (o < 128) ? wq : (o < 256 ? wk : wv);
      Wt[widx] = src[(o & 127) * 128 + c];
    }
  }
}

// ---------------------------------------------------------------------------
// LN stats: per-pixel mean / rsqrt(var+eps).  grid (144,4) x 64 threads.
// ---------------------------------------------------------------------------
__global__ __launch_bounds__(64) void ln_stats_kernel(
    const float* __restrict__ vid, float* __restrict__ mu, float* __restrict__ rs) {
  int pix = blockIdx.x * 64 + threadIdx.x;
  int f = blockIdx.y;
  const float* __restrict__ vp = vid + (size_t)f * 128 * 9216 + pix;
  float s = 0.f, s2 = 0.f;
  #pragma unroll 8
  for (int c = 0; c < 128; ++c) { float x = vp[(size_t)c * 9216]; s += x; s2 += x * x; }
  float m_ = s * (1.f / 128.f);
  float v_ = fmaxf(s2 * (1.f / 128.f) - m_ * m_, 0.f);
  mu[f * 9216 + pix] = m_;
  rs[f * 9216 + pix] = rsqrtf(v_ + 1e-6f);
}

// ---------------------------------------------------------------------------
// QKV GEMM: M-tile=128 pixels, N-tile=128 outputs (= one of q/k/v), K=128 in
// chunks of 32.  256 threads, 8x8 acc/thread.  grid (3, 288).
// Per-thread n-slice = {tx*4..+3} u {64+tx*4..+3} -> conflict-free LDS reads.
// Output layout q/k/v: [t*4+head][pix][c32] fp32.
// ---------------------------------------------------------------------------
__global__ __launch_bounds__(256) void qkv_gemm_kernel(
    const float* __restrict__ vid, const float* __restrict__ mu, const float* __restrict__ rs,
    const float* __restrict__ lnw, const float* __restrict__ lnb,
    const float* __restrict__ Wt, const float* __restrict__ bq, const float* __restrict__ bk,
    const float* __restrict__ bv, float* __restrict__ qb, float* __restrict__ kb,
    float* __restrict__ vb) {
  __shared__ __align__(16) float Xs[32][128];
  __shared__ __align__(16) float Ws[32][128];
  __shared__ float muL[128], rsL[128], lwS[128], lbS[128];
  int tid = threadIdx.x;
  int mt = blockIdx.y;
  int N0 = blockIdx.x * 128;
  int f  = mt / 72;
  int pf = (mt % 72) * 128;

  if (tid < 128) {
    muL[tid] = mu[f * 9216 + pf + tid];
    rsL[tid] = rs[f * 9216 + pf + tid];
  } else {
    int t2 = tid - 128;
    lwS[t2] = lnw[t2];
    lbS[t2] = lnb[t2];
  }

  int tx = tid & 15, ty = tid >> 4;
  int m0 = ty * 8;
  float acc[8][8];
  #pragma unroll
  for (int a = 0; a < 8; ++a)
    #pragma unroll
    for (int b = 0; b < 8; ++b) acc[a][b] = 0.f;

  const size_t vbase = (size_t)f * 128 * 9216 + pf;
  for (int kc = 0; kc < 4; ++kc) {
    __syncthreads();
    #pragma unroll
    for (int it = 0; it < 16; ++it) {
      int i = it * 256 + tid;
      int kk = i >> 7, m = i & 127;
      int c = kc * 32 + kk;
      float x = vid[vbase + (size_t)c * 9216 + m];
      Xs[kk][m] = (x - muL[m]) * rsL[m] * lwS[c] + lbS[c];
    }
    #pragma unroll
    for (int it = 0; it < 16; ++it) {
      int i = it * 256 + tid;
      int kk = i >> 7, n = i & 127;
      Ws[kk][n] = Wt[(size_t)(kc * 32 + kk) * 384 + N0 + n];
    }
    __syncthreads();
    #pragma unroll 4
    for (int kk = 0; kk < 32; ++kk) {
      float xa[8], wa[8];
      *(float4*)&xa[0] = *(const float4*)&Xs[kk][m0];
      *(float4*)&xa[4] = *(const float4*)&Xs[kk][m0 + 4];
      *(float4*)&wa[0] = *(const float4*)&Ws[kk][tx * 4];
      *(float4*)&wa[4] = *(const float4*)&Ws[kk][64 + tx * 4];
      #pragma unroll
      for (int a = 0; a < 8; ++a)
        #pragma unroll
        for (int b = 0; b < 8; ++b)
          acc[a][b] = fmaf(xa[a], wa[b], acc[a][b]);
    }
  }

  int sel = blockIdx.x;
  const float* __restrict__ bias = (sel == 0) ? bq : (sel == 1 ? bk : bv);
  float* __restrict__ dst = (sel == 0) ? qb : (sel == 1 ? kb : vb);
  int nlo = tx * 4, nhi = 64 + tx * 4;
  int hlo = nlo >> 5, clo = nlo & 31;
  int hhi = nhi >> 5, chi = nhi & 31;
  float4 blo = make_float4(bias[nlo], bias[nlo + 1], bias[nlo + 2], bias[nlo + 3]);
  float4 bhi = make_float4(bias[nhi], bias[nhi + 1], bias[nhi + 2], bias[nhi + 3]);
  size_t base_lo = (size_t)(f * 4 + hlo) * 9216 * 32 + clo;
  size_t base_hi = (size_t)(f * 4 + hhi) * 9216 * 32 + chi;
  #pragma unroll
  for (int a = 0; a < 8; ++a) {
    size_t poff = (size_t)(pf + m0 + a) * 32;
    *(float4*)&dst[base_lo + poff] = make_float4(acc[a][0] + blo.x, acc[a][1] + blo.y,
                                                 acc[a][2] + blo.z, acc[a][3] + blo.w);
    *(float4*)&dst[base_hi + poff] = make_float4(acc[a][4] + bhi.x, acc[a][5] + bhi.y,
                                                 acc[a][6] + bhi.z, acc[a][7] + bhi.w);
  }
}

// ---------------------------------------------------------------------------
// search + topk + softmax.  12x12 pixel tile per block, one (t,head).
// s-region 14x14 (box-sum halo), k-region 20x20 staged in LDS (pad 32->36).
// grid (64, 16), 256 threads (196 active for s/topk).
// ---------------------------------------------------------------------------
__global__ __launch_bounds__(256) void search_kernel(
    const float* __restrict__ qb, const float* __restrict__ kb,
    float* __restrict__ wgtb, int* __restrict__ indb) {
  __shared__ __align__(16) float klds[400 * 36];
  __shared__ float slds[196];
  int tid = threadIdx.x;
  int th = blockIdx.y;
  int tile = blockIdx.x;
  int ty0 = (tile >> 3) * 12, tx0 = (tile & 7) * 12;
  const float* __restrict__ kbase = kb + (size_t)th * 9216 * 32;

  for (int i = tid; i < 400 * 8; i += 256) {
    int pix = i >> 3, c4 = i & 7;
    int ry = pix / 20, rx = pix % 20;
    int gy = ty0 - 4 + ry, gx = tx0 - 4 + rx;
    float4 val = make_float4(0.f, 0.f, 0.f, 0.f);
    if ((unsigned)gy < 96u && (unsigned)gx < 96u)
      val = *(const float4*)&kbase[(size_t)(gy * 96 + gx) * 32 + c4 * 4];
    *(float4*)&klds[pix * 36 + c4 * 4] = val;
  }

  int sy = tid / 14, sx = tid % 14;
  bool active = tid < 196;
  int gy = ty0 - 1 + sy, gx = tx0 - 1 + sx;
  bool qok = active && (unsigned)gy < 96u && (unsigned)gx < 96u;
  float4 qv[8];
  #pragma unroll
  for (int j = 0; j < 8; ++j) qv[j] = make_float4(0.f, 0.f, 0.f, 0.f);
  if (qok) {
    const float* __restrict__ qp = qb + ((size_t)th * 9216 + gy * 96 + gx) * 32;
    #pragma unroll
    for (int j = 0; j < 8; ++j) qv[j] = *(const float4*)&qp[j * 4];
  }
  bool inner = active && sy >= 1 && sy <= 12 && sx >= 1 && sx <= 12;
  int py = ty0 + sy - 1, px = tx0 + sx - 1;

  float tv[16]; int tix[16];
  #pragma unroll
  for (int j = 0; j < 16; ++j) { tv[j] = -3.0e38f; tix[j] = 0; }
  __syncthreads();

  for (int oi = 0; oi < 49; ++oi) {
    int dy = oi / 7, dx = oi % 7;
    if (active) {
      const float* __restrict__ kp = &klds[((sy + dy) * 20 + (sx + dx)) * 36];
      float sdot = 0.f;
      #pragma unroll
      for (int j = 0; j < 8; ++j) {
        float4 kv = *(const float4*)&kp[j * 4];
        sdot += qv[j].x * kv.x + qv[j].y * kv.y + qv[j].z * kv.z + qv[j].w * kv.w;
      }
      slds[tid] = sdot;
    }
    __syncthreads();
    if (inner) {
      float sc = 0.f;
      #pragma unroll
      for (int a = 0; a < 3; ++a)
        #pragma unroll
        for (int b = 0; b < 3; ++b)
          sc += slds[(sy - 1 + a) * 14 + (sx - 1 + b)];
      float cv = sc; int ci = oi; bool ins = false;
      #pragma unroll
      for (int j = 0; j < 16; ++j) {
        bool sw = ins || (cv > tv[j]);
        float pv = tv[j]; int pi = tix[j];
        tv[j]  = sw ? cv : pv;
        tix[j] = sw ? ci : pi;
        cv = sw ? pv : cv;
        ci = sw ? pi : ci;
        ins = sw;
      }
    }
    __syncthreads();
  }

  if (inner) {
    float mx = tv[0];
    float e[16], ssum = 0.f;
    #pragma unroll
    for (int j = 0; j < 16; ++j) { e[j] = __expf(tv[j] - mx); ssum += e[j]; }
    float inv = 1.f / ssum;
    size_t base = ((size_t)th * 9216 + py * 96 + px) * 16;
    #pragma unroll
    for (int j = 0; j < 4; ++j) {
      *(float4*)&wgtb[base + j * 4] =
          make_float4(e[j*4] * inv, e[j*4+1] * inv, e[j*4+2] * inv, e[j*4+3] * inv);
      *(int4*)&indb[base + j * 4] = make_int4(tix[j*4], tix[j*4+1], tix[j*4+2], tix[j*4+3]);
    }
  }
}

// ---------------------------------------------------------------------------
// stack build: A[fg][pix][kd][i32] bf16 = wgt * v[nbr];  4 threads per (pix,kd)
// ---------------------------------------------------------------------------
__global__ __launch_bounds__(256) void abuild_kernel(
    const float* __restrict__ vb, const float* __restrict__ wgtb, const int* __restrict__ indb,
    __bf16* __restrict__ Ab, int fbase) {
  int gid = blockIdx.x * 64 + (threadIdx.x >> 2);
  int sub = threadIdx.x & 3;
  int kd  = gid & 15;
  int rest = gid >> 4;
  int pix = rest % 9216;
  int fg  = rest / 9216;           // f_local*4+g
  int th  = fbase * 4 + fg;
  size_t qidx = ((size_t)th * 9216 + pix) * 16 + kd;
  int ind = indb[qidx];
  float wgt = wgtb[qidx];
  int ny = pix / 96 + ind / 7 - 3;
  int nx = pix % 96 + ind % 7 - 3;
  float vals[8] = {0.f, 0.f, 0.f, 0.f, 0.f, 0.f, 0.f, 0.f};
  if ((unsigned)ny < 96u && (unsigned)nx < 96u) {
    const float* __restrict__ vp = &vb[((size_t)th * 9216 + ny * 96 + nx) * 32 + sub * 8];
    *(float4*)&vals[0] = *(const float4*)&vp[0];
    *(float4*)&vals[4] = *(const float4*)&vp[4];
  }
  bf16x8 ov;
  #pragma unroll
  for (int j = 0; j < 8; ++j) ov[j] = (__bf16)(vals[j] * wgt);
  *(bf16x8*)&Ab[(((size_t)fg * 9216 + pix) * 16 + kd) * 32 + sub * 8] = ov;
}

// ---------------------------------------------------------------------------
// implicit-conv GEMM: out[o,h,w] = sum_{d,kd,i} A[p+delta(d)][kd][i]*pw[o,i,kd,d] + b
// 16x16 pixel tile, 18x18 A halo in LDS (row pad 32->40 bf16), 4 waves.
// grid (36, nf*4), 256 threads.
// ---------------------------------------------------------------------------
__global__ __launch_bounds__(256) void proj_kernel(
    const __bf16* __restrict__ Ab, const __bf16* __restrict__ pwt,
    const float* __restrict__ pb, float* __restrict__ outp, int fbase) {
  __shared__ __align__(16) __bf16 Alds[324 * 40];
  __shared__ __align__(16) __bf16 Blds[288 * 40];
  int tid = threadIdx.x;
  int fg = blockIdx.y;
  int g = fg & 3, fl = fg >> 2;
  int tile = blockIdx.x;
  int ty0 = (tile / 6) * 16, tx0 = (tile % 6) * 16;
  int lane = tid & 63, wid = tid >> 6;
  int kg = lane >> 4, lr = lane & 15;

  f32x4 acc[4][2];
  #pragma unroll
  for (int a = 0; a < 4; ++a) {
    acc[a][0] = (f32x4)(0.0f);
    acc[a][1] = (f32x4)(0.0f);
  }

  for (int kd = 0; kd < 16; ++kd) {
    __syncthreads();
    for (int i = tid; i < 1296; i += 256) {
      int pix = i >> 2, c = i & 3;
      int ry = pix / 18, rx = pix % 18;
      int gy2 = ty0 - 1 + ry, gx2 = tx0 - 1 + rx;
      int4 val = make_int4(0, 0, 0, 0);
      if ((unsigned)gy2 < 96u && (unsigned)gx2 < 96u)
        val = *(const int4*)&Ab[(((size_t)fg * 9216 + gy2 * 96 + gx2) * 16 + kd) * 32 + c * 8];
      *(int4*)&Alds[pix * 40 + c * 8] = val;
    }
    {
      const __bf16* __restrict__ bsrc = pwt + (size_t)(g * 16 + kd) * 9216;
      for (int i = tid; i < 1152; i += 256) {
        int row = i >> 2, c = i & 3;
        *(int4*)&Blds[row * 40 + c * 8] = *(const int4*)&bsrc[row * 32 + c * 8];
      }
    }
    __syncthreads();
    #pragma unroll
    for (int d = 0; d < 9; ++d) {
      int dy = d / 3 - 1, dx = d % 3 - 1;
      bf16x8 b0 = *(const bf16x8*)&Blds[(d * 32 + lr) * 40 + kg * 8];
      bf16x8 b1 = *(const bf16x8*)&Blds[(d * 32 + 16 + lr) * 40 + kg * 8];
      #pragma unroll
      for (int mt = 0; mt < 4; ++mt) {
        int ry = wid * 4 + mt + 1 + dy;
        int rx = lr + 1 + dx;
        bf16x8 af = *(const bf16x8*)&Alds[(ry * 18 + rx) * 40 + kg * 8];
        acc[mt][0] = __builtin_amdgcn_mfma_f32_16x16x32_bf16(af, b0, acc[mt][0], 0, 0, 0);
        acc[mt][1] = __builtin_amdgcn_mfma_f32_16x16x32_bf16(af, b1, acc[mt][1], 0, 0, 0);
      }
    }
  }

  int x0 = tx0 + kg * 4;
  int tglob = fbase + fl;
  #pragma unroll
  for (int mt = 0; mt < 4; ++mt) {
    int y = ty0 + wid * 4 + mt;
    #pragma unroll
    for (int nt = 0; nt < 2; ++nt) {
      int o = g * 32 + nt * 16 + lr;
      float bias = pb[o];
      float4 res = make_float4(acc[mt][nt][0] + bias, acc[mt][nt][1] + bias,
                               acc[mt][nt][2] + bias, acc[mt][nt][3] + bias);
      *(float4*)&outp[(size_t)(tglob * 128 + o) * 9216 + y * 96 + x0] = res;
    }
  }
}

// ---------------------------------------------------------------------------
extern "C" void kernel_launch(void* const* d_in, const int* in_sizes, int n_in,
                              void* d_out, int out_size, void* d_ws, size_t ws_size,
                              hipStream_t stream) {
  const float* vid = (const float*)d_in[0];
  const float* lnw = (const float*)d_in[1];
  const float* lnb = (const float*)d_in[2];
  const float* wq  = (const float*)d_in[3];
  const float* bq  = (const float*)d_in[4];
  const float* wk  = (const float*)d_in[5];
  const float* bk  = (const float*)d_in[6];
  const float* wv_ = (const float*)d_in[7];
  const float* bv  = (const float*)d_in[8];
  const float* pw  = (const float*)d_in[9];
  const float* pb  = (const float*)d_in[10];
  float* outp = (float*)d_out;

  const size_t SZ_T  = (size_t)16 * 9216 * 32 * 4;     // q/k/v each
  const size_t SZ_W  = (size_t)16 * 9216 * 16 * 4;     // wgt / ind
  const size_t SZ_A1 = (size_t)4 * 9216 * 16 * 32 * 2; // stack per frame
  const size_t SZ_WT = 128 * 384 * 4;
  const size_t SZ_PW = (size_t)4 * 16 * 9 * 32 * 32 * 2;
  const size_t SZ_MU = (size_t)4 * 9216 * 4;
  const size_t fixed = SZ_T + 2 * SZ_W + SZ_WT + SZ_PW + 2 * SZ_MU;

  int nf = 4;
  while (nf > 1 && (size_t)nf * SZ_A1 + fixed > ws_size) nf >>= 1;

  char* base = (char*)d_ws;
  __bf16* Ab = (__bf16*)base;                 // stack chunk (overlays q,k)
  float* qb = (float*)base;
  float* kb = (float*)(base + SZ_T);
  char* p = base + (size_t)nf * SZ_A1;
  float* vb = (float*)p;        p += SZ_T;
  float* wgtb = (float*)p;      p += SZ_W;
  int*   indb = (int*)p;        p += SZ_W;
  float* Wt = (float*)p;        p += SZ_WT;
  __bf16* pwt = (__bf16*)p;     p += SZ_PW;
  float* mu = (float*)p;        p += SZ_MU;
  float* rs = (float*)p;

  prep_kernel<<<2496, 256, 0, stream>>>(wq, wk, wv_, pw, Wt, pwt);
  ln_stats_kernel<<<dim3(144, 4), 64, 0, stream>>>(vid, mu, rs);
  qkv_gemm_kernel<<<dim3(3, 288), 256, 0, stream>>>(vid, mu, rs, lnw, lnb, Wt, bq, bk, bv,
                                                    qb, kb, vb);
  search_kernel<<<dim3(64, 16), 256, 0, stream>>>(qb, kb, wgtb, indb);
  for (int fb = 0; fb < 4; fb += nf) {
    abuild_kernel<<<nf * 9216, 256, 0, stream>>>(vb, wgtb, indb, Ab, fb);
    proj_kernel<<<dim3(36, nf * 4), 256, 0, stream>>>(Ab, pwt, pb, outp, fb);
  }
}

// Round 3
// 271.520 us; speedup vs baseline: 1.2299x; 1.1473x over previous
//
#include <hip/hip_runtime.h>

// NonLocalAttentionStack on MI355X.
// Dims: B=1, T=4, C=128, H=W=96, NHEADS=4 (c=32/head), WS=7 (49 cands), PS=3, K=16.
// Pipeline: prep -> ln_stats -> QKV (fp32 GEMM, reg-double-buffered) ->
//           search+topk+softmax (fp32) -> fused gather+implicit-conv MFMA GEMM.

typedef float  f32x4  __attribute__((ext_vector_type(4)));
typedef __bf16 bf16x8 __attribute__((ext_vector_type(8)));

// ---------------------------------------------------------------------------
// prep: Wt[c][o=384] = {wq|wk|wv}[o][c];  pwt[g][kd][d=9][o=32][i=32] bf16
// ---------------------------------------------------------------------------
__global__ __launch_bounds__(256) void prep_kernel(
    const float* __restrict__ wq, const float* __restrict__ wk, const float* __restrict__ wv,
    const float* __restrict__ pw, float* __restrict__ Wt, __bf16* __restrict__ pwt) {
  int idx = blockIdx.x * 256 + threadIdx.x;
  const int NPW = 4 * 16 * 9 * 32 * 32;  // 589824
  if (idx < NPW) {
    int i  = idx & 31;
    int ol = (idx >> 5) & 31;
    int d  = (idx >> 10) % 9;
    int r  = (idx >> 10) / 9;   // g*16+kd
    int kd = r & 15;
    int g  = r >> 4;
    int o  = g * 32 + ol;
    pwt[idx] = (__bf16)pw[((o * 32 + i) * 16 + kd) * 9 + d];
  } else {
    int widx = idx - NPW;
    if (widx < 128 * 384) {
      int o = widx % 384;
      int c = widx / 384;
      const float* __restrict__ src = (o < 128) ? wq : (o < 256 ? wk : wv);
      Wt[widx] = src[(o & 127) * 128 + c];
    }
  }
}

// ---------------------------------------------------------------------------
// LN stats: per-pixel mean / rsqrt(var+eps).  grid (144,4) x 64 threads.
// ---------------------------------------------------------------------------
__global__ __launch_bounds__(64) void ln_stats_kernel(
    const float* __restrict__ vid, float* __restrict__ mu, float* __restrict__ rs) {
  int pix = blockIdx.x * 64 + threadIdx.x;
  int f = blockIdx.y;
  const float* __restrict__ vp = vid + (size_t)f * 128 * 9216 + pix;
  float s = 0.f, s2 = 0.f;
  #pragma unroll 8
  for (int c = 0; c < 128; ++c) { float x = vp[(size_t)c * 9216]; s += x; s2 += x * x; }
  float m_ = s * (1.f / 128.f);
  float v_ = fmaxf(s2 * (1.f / 128.f) - m_ * m_, 0.f);
  mu[f * 9216 + pix] = m_;
  rs[f * 9216 + pix] = rsqrtf(v_ + 1e-6f);
}

// ---------------------------------------------------------------------------
// QKV GEMM: 128x128 tile, K=128 in 4x32 chunks, 512 threads (8 waves),
// register double-buffered staging (issue loads before compute phase).
// grid (3, 288); blockIdx.x selects q/k/v.  Per-thread 4x8 acc.
// Output layout q/k/v: [t*4+head][pix][c32] fp32.
// ---------------------------------------------------------------------------
__global__ __launch_bounds__(512) void qkv_gemm_kernel(
    const float* __restrict__ vid, const float* __restrict__ mu, const float* __restrict__ rs,
    const float* __restrict__ lnw, const float* __restrict__ lnb,
    const float* __restrict__ Wt, const float* __restrict__ bq, const float* __restrict__ bk,
    const float* __restrict__ bv, float* __restrict__ qb, float* __restrict__ kb,
    float* __restrict__ vb) {
  __shared__ __align__(16) float Xs[32][128];
  __shared__ __align__(16) float Ws[32][128];
  __shared__ float muL[128], rsL[128], lwS[128], lbS[128];
  int tid = threadIdx.x;
  int mt = blockIdx.y;
  int N0 = blockIdx.x * 128;
  int f  = mt / 72;
  int pf = (mt % 72) * 128;

  if (tid < 128) {
    muL[tid] = mu[f * 9216 + pf + tid];
    rsL[tid] = rs[f * 9216 + pf + tid];
  } else if (tid < 256) {
    int t2 = tid - 128;
    lwS[t2] = lnw[t2];
    lbS[t2] = lnb[t2];
  }

  int tx = tid & 15, ty = tid >> 4;   // ty 0..31
  int m0 = ty * 4;
  int sm = tid & 127;                  // staging column
  int sk = tid >> 7;                   // staging row base (0..3)
  float acc[4][8];
  #pragma unroll
  for (int a = 0; a < 4; ++a)
    #pragma unroll
    for (int b = 0; b < 8; ++b) acc[a][b] = 0.f;

  const size_t vbase = (size_t)f * 128 * 9216 + pf;
  float xr[8], wr[8];

  // prologue: load chunk 0
  #pragma unroll
  for (int it = 0; it < 8; ++it) {
    int kk = sk + 4 * it;
    xr[it] = vid[vbase + (size_t)kk * 9216 + sm];
    wr[it] = Wt[(size_t)kk * 384 + N0 + sm];
  }
  __syncthreads();  // stats visible
  #pragma unroll
  for (int it = 0; it < 8; ++it) {
    int kk = sk + 4 * it;
    Xs[kk][sm] = (xr[it] - muL[sm]) * rsL[sm] * lwS[kk] + lbS[kk];
    Ws[kk][sm] = wr[it];
  }
  __syncthreads();

  for (int kc = 0; kc < 4; ++kc) {
    if (kc < 3) {
      #pragma unroll
      for (int it = 0; it < 8; ++it) {
        int kk = sk + 4 * it;
        int c = (kc + 1) * 32 + kk;
        xr[it] = vid[vbase + (size_t)c * 9216 + sm];
        wr[it] = Wt[(size_t)c * 384 + N0 + sm];
      }
    }
    #pragma unroll 4
    for (int kk = 0; kk < 32; ++kk) {
      float xa[4], wa[8];
      *(float4*)&xa[0] = *(const float4*)&Xs[kk][m0];
      *(float4*)&wa[0] = *(const float4*)&Ws[kk][tx * 4];
      *(float4*)&wa[4] = *(const float4*)&Ws[kk][64 + tx * 4];
      #pragma unroll
      for (int a = 0; a < 4; ++a)
        #pragma unroll
        for (int b = 0; b < 8; ++b)
          acc[a][b] = fmaf(xa[a], wa[b], acc[a][b]);
    }
    if (kc < 3) {
      __syncthreads();
      #pragma unroll
      for (int it = 0; it < 8; ++it) {
        int kk = sk + 4 * it;
        int c = (kc + 1) * 32 + kk;
        Xs[kk][sm] = (xr[it] - muL[sm]) * rsL[sm] * lwS[c] + lbS[c];
        Ws[kk][sm] = wr[it];
      }
      __syncthreads();
    }
  }

  int sel = blockIdx.x;
  const float* __restrict__ bias = (sel == 0) ? bq : (sel == 1 ? bk : bv);
  float* __restrict__ dst = (sel == 0) ? qb : (sel == 1 ? kb : vb);
  int nlo = tx * 4, nhi = 64 + tx * 4;
  int hlo = nlo >> 5, clo = nlo & 31;
  int hhi = nhi >> 5, chi = nhi & 31;
  float4 blo = make_float4(bias[nlo], bias[nlo + 1], bias[nlo + 2], bias[nlo + 3]);
  float4 bhi = make_float4(bias[nhi], bias[nhi + 1], bias[nhi + 2], bias[nhi + 3]);
  size_t base_lo = (size_t)(f * 4 + hlo) * 9216 * 32 + clo;
  size_t base_hi = (size_t)(f * 4 + hhi) * 9216 * 32 + chi;
  #pragma unroll
  for (int a = 0; a < 4; ++a) {
    size_t poff = (size_t)(pf + m0 + a) * 32;
    *(float4*)&dst[base_lo + poff] = make_float4(acc[a][0] + blo.x, acc[a][1] + blo.y,
                                                 acc[a][2] + blo.z, acc[a][3] + blo.w);
    *(float4*)&dst[base_hi + poff] = make_float4(acc[a][4] + bhi.x, acc[a][5] + bhi.y,
                                                 acc[a][6] + bhi.z, acc[a][7] + bhi.w);
  }
}

// ---------------------------------------------------------------------------
// search + topk + softmax.  12x12 pixel tile per block, one (t,head).
// grid (64, 16), 256 threads (196 active for s/topk).
// ---------------------------------------------------------------------------
__global__ __launch_bounds__(256) void search_kernel(
    const float* __restrict__ qb, const float* __restrict__ kb,
    float* __restrict__ wgtb, int* __restrict__ indb) {
  __shared__ __align__(16) float klds[400 * 36];
  __shared__ float slds[196];
  int tid = threadIdx.x;
  int th = blockIdx.y;
  int tile = blockIdx.x;
  int ty0 = (tile >> 3) * 12, tx0 = (tile & 7) * 12;
  const float* __restrict__ kbase = kb + (size_t)th * 9216 * 32;

  for (int i = tid; i < 400 * 8; i += 256) {
    int pix = i >> 3, c4 = i & 7;
    int ry = pix / 20, rx = pix % 20;
    int gy = ty0 - 4 + ry, gx = tx0 - 4 + rx;
    float4 val = make_float4(0.f, 0.f, 0.f, 0.f);
    if ((unsigned)gy < 96u && (unsigned)gx < 96u)
      val = *(const float4*)&kbase[(size_t)(gy * 96 + gx) * 32 + c4 * 4];
    *(float4*)&klds[pix * 36 + c4 * 4] = val;
  }

  int sy = tid / 14, sx = tid % 14;
  bool active = tid < 196;
  int gy = ty0 - 1 + sy, gx = tx0 - 1 + sx;
  bool qok = active && (unsigned)gy < 96u && (unsigned)gx < 96u;
  float4 qv[8];
  #pragma unroll
  for (int j = 0; j < 8; ++j) qv[j] = make_float4(0.f, 0.f, 0.f, 0.f);
  if (qok) {
    const float* __restrict__ qp = qb + ((size_t)th * 9216 + gy * 96 + gx) * 32;
    #pragma unroll
    for (int j = 0; j < 8; ++j) qv[j] = *(const float4*)&qp[j * 4];
  }
  bool inner = active && sy >= 1 && sy <= 12 && sx >= 1 && sx <= 12;
  int py = ty0 + sy - 1, px = tx0 + sx - 1;

  float tv[16]; int tix[16];
  #pragma unroll
  for (int j = 0; j < 16; ++j) { tv[j] = -3.0e38f; tix[j] = 0; }
  __syncthreads();

  for (int oi = 0; oi < 49; ++oi) {
    int dy = oi / 7, dx = oi % 7;
    if (active) {
      const float* __restrict__ kp = &klds[((sy + dy) * 20 + (sx + dx)) * 36];
      float sdot = 0.f;
      #pragma unroll
      for (int j = 0; j < 8; ++j) {
        float4 kv = *(const float4*)&kp[j * 4];
        sdot += qv[j].x * kv.x + qv[j].y * kv.y + qv[j].z * kv.z + qv[j].w * kv.w;
      }
      slds[tid] = sdot;
    }
    __syncthreads();
    if (inner) {
      float sc = 0.f;
      #pragma unroll
      for (int a = 0; a < 3; ++a)
        #pragma unroll
        for (int b = 0; b < 3; ++b)
          sc += slds[(sy - 1 + a) * 14 + (sx - 1 + b)];
      float cv = sc; int ci = oi; bool ins = false;
      #pragma unroll
      for (int j = 0; j < 16; ++j) {
        bool sw = ins || (cv > tv[j]);
        float pv = tv[j]; int pi = tix[j];
        tv[j]  = sw ? cv : pv;
        tix[j] = sw ? ci : pi;
        cv = sw ? pv : cv;
        ci = sw ? pi : ci;
        ins = sw;
      }
    }
    __syncthreads();
  }

  if (inner) {
    float mx = tv[0];
    float e[16], ssum = 0.f;
    #pragma unroll
    for (int j = 0; j < 16; ++j) { e[j] = __expf(tv[j] - mx); ssum += e[j]; }
    float inv = 1.f / ssum;
    size_t base = ((size_t)th * 9216 + py * 96 + px) * 16;
    #pragma unroll
    for (int j = 0; j < 4; ++j) {
      *(float4*)&wgtb[base + j * 4] =
          make_float4(e[j*4] * inv, e[j*4+1] * inv, e[j*4+2] * inv, e[j*4+3] * inv);
      *(int4*)&indb[base + j * 4] = make_int4(tix[j*4], tix[j*4+1], tix[j*4+2], tix[j*4+3]);
    }
  }
}

// ---------------------------------------------------------------------------
// fused gather + implicit-conv GEMM:
//   out[o,h,w] = sum_{d,kd,i} wgt[p'][kd]*v[nbr(p',kd)][i] * pw[o,i,kd,d] + b
// Per kd: gather-stage A-halo (18x18 px x 32 ch, weighted, bf16) + B, then MFMA.
// 16x16 pixel tile, row pad 32->40 bf16, 4 waves.  grid (36, 16), 256 threads.
// ---------------------------------------------------------------------------
__global__ __launch_bounds__(256) void proj_kernel(
    const float* __restrict__ vb, const float* __restrict__ wgtb, const int* __restrict__ indb,
    const __bf16* __restrict__ pwt, const float* __restrict__ pb, float* __restrict__ outp) {
  __shared__ __align__(16) __bf16 Alds[324 * 40];
  __shared__ __align__(16) __bf16 Blds[288 * 40];
  int tid = threadIdx.x;
  int th = blockIdx.y;             // f*4+g
  int g = th & 3;
  int tile = blockIdx.x;
  int ty0 = (tile / 6) * 16, tx0 = (tile % 6) * 16;
  int lane = tid & 63, wid = tid >> 6;
  int kg = lane >> 4, lr = lane & 15;

  const float* __restrict__ vbase = vb + (size_t)th * 9216 * 32;
  const float* __restrict__ wbase = wgtb + (size_t)th * 9216 * 16;
  const int*   __restrict__ ibase = indb + (size_t)th * 9216 * 16;

  f32x4 acc[4][2];
  #pragma unroll
  for (int a = 0; a < 4; ++a) {
    acc[a][0] = (f32x4)(0.0f);
    acc[a][1] = (f32x4)(0.0f);
  }

  for (int kd = 0; kd < 16; ++kd) {
    __syncthreads();
    // gather-stage A halo (324 px, 2 threads/px: 16 ch each), weighted bf16
    for (int i = tid; i < 648; i += 256) {
      int px = i >> 1, sub = i & 1;
      int ry = px / 18, rx = px % 18;
      int gy = ty0 - 1 + ry, gx = tx0 - 1 + rx;
      float vals[16];
      #pragma unroll
      for (int j = 0; j < 16; ++j) vals[j] = 0.f;
      float wgt = 0.f;
      if ((unsigned)gy < 96u && (unsigned)gx < 96u) {
        size_t q = (size_t)(gy * 96 + gx) * 16 + kd;
        int ind = ibase[q];
        wgt = wbase[q];
        int ny = gy + ind / 7 - 3, nx = gx + ind % 7 - 3;
        if ((unsigned)ny < 96u && (unsigned)nx < 96u) {
          const float* __restrict__ vp = vbase + (size_t)(ny * 96 + nx) * 32 + sub * 16;
          *(float4*)&vals[0]  = *(const float4*)&vp[0];
          *(float4*)&vals[4]  = *(const float4*)&vp[4];
          *(float4*)&vals[8]  = *(const float4*)&vp[8];
          *(float4*)&vals[12] = *(const float4*)&vp[12];
        }
      }
      __bf16 tmp[16];
      #pragma unroll
      for (int j = 0; j < 16; ++j) tmp[j] = (__bf16)(vals[j] * wgt);
      __bf16* dst = &Alds[px * 40 + sub * 16];
      *(int4*)&dst[0] = *(const int4*)&tmp[0];
      *(int4*)&dst[8] = *(const int4*)&tmp[8];
    }
    // stage B: 9 taps x 32 outs x 32 ch for this (g,kd)
    {
      const __bf16* __restrict__ bsrc = pwt + (size_t)(g * 16 + kd) * 9216;
      for (int i = tid; i < 1152; i += 256) {
        int row = i >> 2, c = i & 3;
        *(int4*)&Blds[row * 40 + c * 8] = *(const int4*)&bsrc[row * 32 + c * 8];
      }
    }
    __syncthreads();
    #pragma unroll
    for (int d = 0; d < 9; ++d) {
      int dy = d / 3 - 1, dx = d % 3 - 1;
      bf16x8 b0 = *(const bf16x8*)&Blds[(d * 32 + lr) * 40 + kg * 8];
      bf16x8 b1 = *(const bf16x8*)&Blds[(d * 32 + 16 + lr) * 40 + kg * 8];
      #pragma unroll
      for (int mt = 0; mt < 4; ++mt) {
        int ry = wid * 4 + mt + 1 + dy;
        int rx = lr + 1 + dx;
        bf16x8 af = *(const bf16x8*)&Alds[(ry * 18 + rx) * 40 + kg * 8];
        acc[mt][0] = __builtin_amdgcn_mfma_f32_16x16x32_bf16(af, b0, acc[mt][0], 0, 0, 0);
        acc[mt][1] = __builtin_amdgcn_mfma_f32_16x16x32_bf16(af, b1, acc[mt][1], 0, 0, 0);
      }
    }
  }

  int x0 = tx0 + kg * 4;
  int f = th >> 2;
  #pragma unroll
  for (int mt = 0; mt < 4; ++mt) {
    int y = ty0 + wid * 4 + mt;
    #pragma unroll
    for (int nt = 0; nt < 2; ++nt) {
      int o = g * 32 + nt * 16 + lr;
      float bias = pb[o];
      float4 res = make_float4(acc[mt][nt][0] + bias, acc[mt][nt][1] + bias,
                               acc[mt][nt][2] + bias, acc[mt][nt][3] + bias);
      *(float4*)&outp[(size_t)(f * 128 + o) * 9216 + y * 96 + x0] = res;
    }
  }
}

// ---------------------------------------------------------------------------
extern "C" void kernel_launch(void* const* d_in, const int* in_sizes, int n_in,
                              void* d_out, int out_size, void* d_ws, size_t ws_size,
                              hipStream_t stream) {
  const float* vid = (const float*)d_in[0];
  const float* lnw = (const float*)d_in[1];
  const float* lnb = (const float*)d_in[2];
  const float* wq  = (const float*)d_in[3];
  const float* bq  = (const float*)d_in[4];
  const float* wk  = (const float*)d_in[5];
  const float* bk  = (const float*)d_in[6];
  const float* wv_ = (const float*)d_in[7];
  const float* bv  = (const float*)d_in[8];
  const float* pw  = (const float*)d_in[9];
  const float* pb  = (const float*)d_in[10];
  float* outp = (float*)d_out;

  const size_t SZ_T  = (size_t)16 * 9216 * 32 * 4;     // q/k/v each
  const size_t SZ_W  = (size_t)16 * 9216 * 16 * 4;     // wgt / ind
  const size_t SZ_WT = 128 * 384 * 4;
  const size_t SZ_PW = (size_t)4 * 16 * 9 * 32 * 32 * 2;
  const size_t SZ_MU = (size_t)4 * 9216 * 4;

  char* p = (char*)d_ws;
  float* qb = (float*)p;        p += SZ_T;
  float* kb = (float*)p;        p += SZ_T;
  float* vb = (float*)p;        p += SZ_T;
  float* wgtb = (float*)p;      p += SZ_W;
  int*   indb = (int*)p;        p += SZ_W;
  float* Wt = (float*)p;        p += SZ_WT;
  __bf16* pwt = (__bf16*)p;     p += SZ_PW;
  float* mu = (float*)p;        p += SZ_MU;
  float* rs = (float*)p;

  prep_kernel<<<2496, 256, 0, stream>>>(wq, wk, wv_, pw, Wt, pwt);
  ln_stats_kernel<<<dim3(144, 4), 64, 0, stream>>>(vid, mu, rs);
  qkv_gemm_kernel<<<dim3(3, 288), 512, 0, stream>>>(vid, mu, rs, lnw, lnb, Wt, bq, bk, bv,
                                                    qb, kb, vb);
  search_kernel<<<dim3(64, 16), 256, 0, stream>>>(qb, kb, wgtb, indb);
  proj_kernel<<<dim3(36, 16), 256, 0, stream>>>(vb, wgtb, indb, pwt, pb, outp);
}

// Round 4
// 240.045 us; speedup vs baseline: 1.3912x; 1.1311x over previous
//
#include <hip/hip_runtime.h>

// NonLocalAttentionStack on MI355X.
// Dims: B=1, T=4, C=128, H=W=96, NHEADS=4 (c=32/head), WS=7 (49 cands), PS=3, K=16.
// Pipeline: prep -> ln_stats -> QKV (fp32 GEMM; v output bf16) ->
//           search+topk+softmax (fp32) -> fused gather+implicit-conv MFMA GEMM
//           (XCD-swizzled, T14 reg-prefetch of next-kd gather).

typedef float  f32x4  __attribute__((ext_vector_type(4)));
typedef __bf16 bf16x8 __attribute__((ext_vector_type(8)));
typedef __bf16 bf16x4 __attribute__((ext_vector_type(4)));

// ---------------------------------------------------------------------------
// prep: Wt[c][o=384] = {wq|wk|wv}[o][c];  pwt[g][kd][d=9][o=32][i=32] bf16
// ---------------------------------------------------------------------------
__global__ __launch_bounds__(256) void prep_kernel(
    const float* __restrict__ wq, const float* __restrict__ wk, const float* __restrict__ wv,
    const float* __restrict__ pw, float* __restrict__ Wt, __bf16* __restrict__ pwt) {
  int idx = blockIdx.x * 256 + threadIdx.x;
  const int NPW = 4 * 16 * 9 * 32 * 32;  // 589824
  if (idx < NPW) {
    int i  = idx & 31;
    int ol = (idx >> 5) & 31;
    int d  = (idx >> 10) % 9;
    int r  = (idx >> 10) / 9;   // g*16+kd
    int kd = r & 15;
    int g  = r >> 4;
    int o  = g * 32 + ol;
    pwt[idx] = (__bf16)pw[((o * 32 + i) * 16 + kd) * 9 + d];
  } else {
    int widx = idx - NPW;
    if (widx < 128 * 384) {
      int o = widx % 384;
      int c = widx / 384;
      const float* __restrict__ src = (o < 128) ? wq : (o < 256 ? wk : wv);
      Wt[widx] = src[(o & 127) * 128 + c];
    }
  }
}

// ---------------------------------------------------------------------------
// LN stats: per-pixel mean / rsqrt(var+eps).  grid (144,4) x 64 threads.
// ---------------------------------------------------------------------------
__global__ __launch_bounds__(64) void ln_stats_kernel(
    const float* __restrict__ vid, float* __restrict__ mu, float* __restrict__ rs) {
  int pix = blockIdx.x * 64 + threadIdx.x;
  int f = blockIdx.y;
  const float* __restrict__ vp = vid + (size_t)f * 128 * 9216 + pix;
  float s = 0.f, s2 = 0.f;
  #pragma unroll 8
  for (int c = 0; c < 128; ++c) { float x = vp[(size_t)c * 9216]; s += x; s2 += x * x; }
  float m_ = s * (1.f / 128.f);
  float v_ = fmaxf(s2 * (1.f / 128.f) - m_ * m_, 0.f);
  mu[f * 9216 + pix] = m_;
  rs[f * 9216 + pix] = rsqrtf(v_ + 1e-6f);
}

// ---------------------------------------------------------------------------
// QKV GEMM: 128x128 tile, K=128 in 4x32 chunks, 512 threads (8 waves),
// register double-buffered staging.  grid (3, 288); blockIdx.x selects q/k/v.
// q,k: fp32 [t*4+head][pix][c32].  v: bf16 same layout.
// ---------------------------------------------------------------------------
__global__ __launch_bounds__(512) void qkv_gemm_kernel(
    const float* __restrict__ vid, const float* __restrict__ mu, const float* __restrict__ rs,
    const float* __restrict__ lnw, const float* __restrict__ lnb,
    const float* __restrict__ Wt, const float* __restrict__ bq, const float* __restrict__ bk,
    const float* __restrict__ bv, float* __restrict__ qb, float* __restrict__ kb,
    __bf16* __restrict__ vbbf) {
  __shared__ __align__(16) float Xs[32][128];
  __shared__ __align__(16) float Ws[32][128];
  __shared__ float muL[128], rsL[128], lwS[128], lbS[128];
  int tid = threadIdx.x;
  int mt = blockIdx.y;
  int N0 = blockIdx.x * 128;
  int f  = mt / 72;
  int pf = (mt % 72) * 128;

  if (tid < 128) {
    muL[tid] = mu[f * 9216 + pf + tid];
    rsL[tid] = rs[f * 9216 + pf + tid];
  } else if (tid < 256) {
    int t2 = tid - 128;
    lwS[t2] = lnw[t2];
    lbS[t2] = lnb[t2];
  }

  int tx = tid & 15, ty = tid >> 4;   // ty 0..31
  int m0 = ty * 4;
  int sm = tid & 127;                  // staging column
  int sk = tid >> 7;                   // staging row base (0..3)
  float acc[4][8];
  #pragma unroll
  for (int a = 0; a < 4; ++a)
    #pragma unroll
    for (int b = 0; b < 8; ++b) acc[a][b] = 0.f;

  const size_t vbase = (size_t)f * 128 * 9216 + pf;
  float xr[8], wr[8];

  #pragma unroll
  for (int it = 0; it < 8; ++it) {
    int kk = sk + 4 * it;
    xr[it] = vid[vbase + (size_t)kk * 9216 + sm];
    wr[it] = Wt[(size_t)kk * 384 + N0 + sm];
  }
  __syncthreads();
  #pragma unroll
  for (int it = 0; it < 8; ++it) {
    int kk = sk + 4 * it;
    Xs[kk][sm] = (xr[it] - muL[sm]) * rsL[sm] * lwS[kk] + lbS[kk];
    Ws[kk][sm] = wr[it];
  }
  __syncthreads();

  for (int kc = 0; kc < 4; ++kc) {
    if (kc < 3) {
      #pragma unroll
      for (int it = 0; it < 8; ++it) {
        int kk = sk + 4 * it;
        int c = (kc + 1) * 32 + kk;
        xr[it] = vid[vbase + (size_t)c * 9216 + sm];
        wr[it] = Wt[(size_t)c * 384 + N0 + sm];
      }
    }
    #pragma unroll 4
    for (int kk = 0; kk < 32; ++kk) {
      float xa[4], wa[8];
      *(float4*)&xa[0] = *(const float4*)&Xs[kk][m0];
      *(float4*)&wa[0] = *(const float4*)&Ws[kk][tx * 4];
      *(float4*)&wa[4] = *(const float4*)&Ws[kk][64 + tx * 4];
      #pragma unroll
      for (int a = 0; a < 4; ++a)
        #pragma unroll
        for (int b = 0; b < 8; ++b)
          acc[a][b] = fmaf(xa[a], wa[b], acc[a][b]);
    }
    if (kc < 3) {
      __syncthreads();
      #pragma unroll
      for (int it = 0; it < 8; ++it) {
        int kk = sk + 4 * it;
        int c = (kc + 1) * 32 + kk;
        Xs[kk][sm] = (xr[it] - muL[sm]) * rsL[sm] * lwS[c] + lbS[c];
        Ws[kk][sm] = wr[it];
      }
      __syncthreads();
    }
  }

  int sel = blockIdx.x;
  int nlo = tx * 4, nhi = 64 + tx * 4;
  int hlo = nlo >> 5, clo = nlo & 31;
  int hhi = nhi >> 5, chi = nhi & 31;
  const float* __restrict__ bias = (sel == 0) ? bq : (sel == 1 ? bk : bv);
  float4 blo = make_float4(bias[nlo], bias[nlo + 1], bias[nlo + 2], bias[nlo + 3]);
  float4 bhi = make_float4(bias[nhi], bias[nhi + 1], bias[nhi + 2], bias[nhi + 3]);
  size_t base_lo = (size_t)(f * 4 + hlo) * 9216 * 32 + clo;
  size_t base_hi = (size_t)(f * 4 + hhi) * 9216 * 32 + chi;
  if (sel < 2) {
    float* __restrict__ dst = (sel == 0) ? qb : kb;
    #pragma unroll
    for (int a = 0; a < 4; ++a) {
      size_t poff = (size_t)(pf + m0 + a) * 32;
      *(float4*)&dst[base_lo + poff] = make_float4(acc[a][0] + blo.x, acc[a][1] + blo.y,
                                                   acc[a][2] + blo.z, acc[a][3] + blo.w);
      *(float4*)&dst[base_hi + poff] = make_float4(acc[a][4] + bhi.x, acc[a][5] + bhi.y,
                                                   acc[a][6] + bhi.z, acc[a][7] + bhi.w);
    }
  } else {
    #pragma unroll
    for (int a = 0; a < 4; ++a) {
      size_t poff = (size_t)(pf + m0 + a) * 32;
      bf16x4 lo4, hi4;
      lo4[0] = (__bf16)(acc[a][0] + blo.x); lo4[1] = (__bf16)(acc[a][1] + blo.y);
      lo4[2] = (__bf16)(acc[a][2] + blo.z); lo4[3] = (__bf16)(acc[a][3] + blo.w);
      hi4[0] = (__bf16)(acc[a][4] + bhi.x); hi4[1] = (__bf16)(acc[a][5] + bhi.y);
      hi4[2] = (__bf16)(acc[a][6] + bhi.z); hi4[3] = (__bf16)(acc[a][7] + bhi.w);
      *(bf16x4*)&vbbf[base_lo + poff] = lo4;
      *(bf16x4*)&vbbf[base_hi + poff] = hi4;
    }
  }
}

// ---------------------------------------------------------------------------
// search + topk + softmax.  12x12 pixel tile per block, one (t,head).
// grid (64, 16), 256 threads (196 active for s/topk).
// ---------------------------------------------------------------------------
__global__ __launch_bounds__(256) void search_kernel(
    const float* __restrict__ qb, const float* __restrict__ kb,
    float* __restrict__ wgtb, int* __restrict__ indb) {
  __shared__ __align__(16) float klds[400 * 36];
  __shared__ float slds[196];
  int tid = threadIdx.x;
  int th = blockIdx.y;
  int tile = blockIdx.x;
  int ty0 = (tile >> 3) * 12, tx0 = (tile & 7) * 12;
  const float* __restrict__ kbase = kb + (size_t)th * 9216 * 32;

  for (int i = tid; i < 400 * 8; i += 256) {
    int pix = i >> 3, c4 = i & 7;
    int ry = pix / 20, rx = pix % 20;
    int gy = ty0 - 4 + ry, gx = tx0 - 4 + rx;
    float4 val = make_float4(0.f, 0.f, 0.f, 0.f);
    if ((unsigned)gy < 96u && (unsigned)gx < 96u)
      val = *(const float4*)&kbase[(size_t)(gy * 96 + gx) * 32 + c4 * 4];
    *(float4*)&klds[pix * 36 + c4 * 4] = val;
  }

  int sy = tid / 14, sx = tid % 14;
  bool active = tid < 196;
  int gy = ty0 - 1 + sy, gx = tx0 - 1 + sx;
  bool qok = active && (unsigned)gy < 96u && (unsigned)gx < 96u;
  float4 qv[8];
  #pragma unroll
  for (int j = 0; j < 8; ++j) qv[j] = make_float4(0.f, 0.f, 0.f, 0.f);
  if (qok) {
    const float* __restrict__ qp = qb + ((size_t)th * 9216 + gy * 96 + gx) * 32;
    #pragma unroll
    for (int j = 0; j < 8; ++j) qv[j] = *(const float4*)&qp[j * 4];
  }
  bool inner = active && sy >= 1 && sy <= 12 && sx >= 1 && sx <= 12;
  int py = ty0 + sy - 1, px = tx0 + sx - 1;

  float tv[16]; int tix[16];
  #pragma unroll
  for (int j = 0; j < 16; ++j) { tv[j] = -3.0e38f; tix[j] = 0; }
  __syncthreads();

  for (int oi = 0; oi < 49; ++oi) {
    int dy = oi / 7, dx = oi % 7;
    if (active) {
      const float* __restrict__ kp = &klds[((sy + dy) * 20 + (sx + dx)) * 36];
      float sdot = 0.f;
      #pragma unroll
      for (int j = 0; j < 8; ++j) {
        float4 kv = *(const float4*)&kp[j * 4];
        sdot += qv[j].x * kv.x + qv[j].y * kv.y + qv[j].z * kv.z + qv[j].w * kv.w;
      }
      slds[tid] = sdot;
    }
    __syncthreads();
    if (inner) {
      float sc = 0.f;
      #pragma unroll
      for (int a = 0; a < 3; ++a)
        #pragma unroll
        for (int b = 0; b < 3; ++b)
          sc += slds[(sy - 1 + a) * 14 + (sx - 1 + b)];
      float cv = sc; int ci = oi; bool ins = false;
      #pragma unroll
      for (int j = 0; j < 16; ++j) {
        bool sw = ins || (cv > tv[j]);
        float pv = tv[j]; int pi = tix[j];
        tv[j]  = sw ? cv : pv;
        tix[j] = sw ? ci : pi;
        cv = sw ? pv : cv;
        ci = sw ? pi : ci;
        ins = sw;
      }
    }
    __syncthreads();
  }

  if (inner) {
    float mx = tv[0];
    float e[16], ssum = 0.f;
    #pragma unroll
    for (int j = 0; j < 16; ++j) { e[j] = __expf(tv[j] - mx); ssum += e[j]; }
    float inv = 1.f / ssum;
    size_t base = ((size_t)th * 9216 + py * 96 + px) * 16;
    #pragma unroll
    for (int j = 0; j < 4; ++j) {
      *(float4*)&wgtb[base + j * 4] =
          make_float4(e[j*4] * inv, e[j*4+1] * inv, e[j*4+2] * inv, e[j*4+3] * inv);
      *(int4*)&indb[base + j * 4] = make_int4(tix[j*4], tix[j*4+1], tix[j*4+2], tix[j*4+3]);
    }
  }
}

// ---------------------------------------------------------------------------
// fused gather + implicit-conv GEMM, XCD-swizzled, T14 reg-prefetch.
// grid 576 (1D), 512 threads (8 waves).  16x16 px tile, 18x18 halo.
// Per kd: stage prefetched v*wgt (bf16) -> Alds, B -> Blds, prefetch kd+1,
// then 9-tap MFMA.  wg = (bid%8)*72 + bid/8 -> each XCD owns 2 th-slices.
// ---------------------------------------------------------------------------
__global__ __launch_bounds__(512) void proj_kernel(
    const __bf16* __restrict__ vb, const float* __restrict__ wgtb, const int* __restrict__ indb,
    const __bf16* __restrict__ pwt, const float* __restrict__ pb, float* __restrict__ outp) {
  __shared__ __align__(16) __bf16 Alds[324 * 40];
  __shared__ __align__(16) __bf16 Blds[288 * 40];
  int tid = threadIdx.x;
  int bid = blockIdx.x;
  int wg = (bid & 7) * 72 + (bid >> 3);   // XCD-contiguous remap (576 = 8*72)
  int th = wg / 36;                        // f*4+g
  int tile = wg % 36;
  int g = th & 3;
  int ty0 = (tile / 6) * 16, tx0 = (tile % 6) * 16;
  int lane = tid & 63, wid = tid >> 6;     // wid 0..7
  int kg = lane >> 4, lr = lane & 15;

  // gather assignment: one halo pixel per thread (tid < 324)
  bool gact = tid < 324;
  int ry = tid / 18, rx = tid % 18;
  int gy = ty0 - 1 + ry, gx = tx0 - 1 + rx;
  bool inb = gact && (unsigned)gy < 96u && (unsigned)gx < 96u;
  const __bf16* __restrict__ vbase = vb + (size_t)th * 9216 * 32;
  size_t pxoff = inb ? (size_t)(gy * 96 + gx) : 0;
  const int*   __restrict__ ibase = indb + ((size_t)th * 9216 + pxoff) * 16;
  const float* __restrict__ wbase = wgtb + ((size_t)th * 9216 + pxoff) * 16;

  f32x4 acc[2][2];
  acc[0][0] = (f32x4)(0.0f); acc[0][1] = (f32x4)(0.0f);
  acc[1][0] = (f32x4)(0.0f); acc[1][1] = (f32x4)(0.0f);

  int4 iw_i = make_int4(0, 0, 0, 0);
  float4 iw_w = make_float4(0.f, 0.f, 0.f, 0.f);
  int4 vr[4];
  vr[0] = vr[1] = vr[2] = vr[3] = make_int4(0, 0, 0, 0);
  float wcur = 0.f;

  // prologue: iw block 0 + v(kd=0)
  if (inb) {
    iw_i = *(const int4*)&ibase[0];
    iw_w = *(const float4*)&wbase[0];
    int ind0 = iw_i.x;
    int ny = gy + ind0 / 7 - 3, nx = gx + ind0 % 7 - 3;
    if ((unsigned)ny < 96u && (unsigned)nx < 96u) {
      const int4* __restrict__ vp = (const int4*)(vbase + (size_t)(ny * 96 + nx) * 32);
      vr[0] = vp[0]; vr[1] = vp[1]; vr[2] = vp[2]; vr[3] = vp[3];
    }
    wcur = iw_w.x;
  }

  for (int kdb = 0; kdb < 4; ++kdb) {
    #pragma unroll
    for (int kb = 0; kb < 4; ++kb) {
      int kd = kdb * 4 + kb;
      __syncthreads();   // previous MFMA done reading Alds/Blds
      // stage A: weighted bf16 products from prefetched regs
      if (gact) {
        __bf16 tmp[32];
        #pragma unroll
        for (int wv = 0; wv < 4; ++wv) {
          unsigned u0 = (unsigned)vr[wv].x, u1 = (unsigned)vr[wv].y;
          unsigned u2 = (unsigned)vr[wv].z, u3 = (unsigned)vr[wv].w;
          unsigned uu[4] = {u0, u1, u2, u3};
          #pragma unroll
          for (int j2 = 0; j2 < 4; ++j2) {
            float lo = __uint_as_float(uu[j2] << 16);
            float hi = __uint_as_float(uu[j2] & 0xffff0000u);
            tmp[wv * 8 + j2 * 2]     = (__bf16)(lo * wcur);
            tmp[wv * 8 + j2 * 2 + 1] = (__bf16)(hi * wcur);
          }
        }
        __bf16* dst = &Alds[tid * 40];
        *(int4*)&dst[0]  = *(const int4*)&tmp[0];
        *(int4*)&dst[8]  = *(const int4*)&tmp[8];
        *(int4*)&dst[16] = *(const int4*)&tmp[16];
        *(int4*)&dst[24] = *(const int4*)&tmp[24];
      }
      // stage B: 9 taps x 32 outs x 32 ch for this (g,kd)
      {
        const __bf16* __restrict__ bsrc = pwt + (size_t)(g * 16 + kd) * 9216;
        #pragma unroll
        for (int itb = 0; itb < 3; ++itb) {
          int i = itb * 512 + tid;
          if (i < 1152) {
            int row = i >> 2, c = i & 3;
            *(int4*)&Blds[row * 40 + c * 8] = *(const int4*)&bsrc[row * 32 + c * 8];
          }
        }
      }
      __syncthreads();
      // T14: prefetch gather for kd+1 (loads overlap the MFMAs below)
      if (kd < 15) {
        int indn; float wn;
        if (kb == 3) {
          if (inb) {
            iw_i = *(const int4*)&ibase[kd + 1];
            iw_w = *(const float4*)&wbase[kd + 1];
          }
          indn = iw_i.x; wn = iw_w.x;
        } else {
          indn = (kb == 0) ? iw_i.y : (kb == 1) ? iw_i.z : iw_i.w;
          wn   = (kb == 0) ? iw_w.y : (kb == 1) ? iw_w.z : iw_w.w;
        }
        vr[0] = vr[1] = vr[2] = vr[3] = make_int4(0, 0, 0, 0);
        if (inb) {
          int ny = gy + indn / 7 - 3, nx = gx + indn % 7 - 3;
          if ((unsigned)ny < 96u && (unsigned)nx < 96u) {
            const int4* __restrict__ vp = (const int4*)(vbase + (size_t)(ny * 96 + nx) * 32);
            vr[0] = vp[0]; vr[1] = vp[1]; vr[2] = vp[2]; vr[3] = vp[3];
          }
        }
        wcur = wn;
      }
      // MFMA: 9 taps, 2 rows/wave, 32 outs
      #pragma unroll
      for (int d = 0; d < 9; ++d) {
        int dy = d / 3 - 1, dx = d % 3 - 1;
        bf16x8 b0 = *(const bf16x8*)&Blds[(d * 32 + lr) * 40 + kg * 8];
        bf16x8 b1 = *(const bf16x8*)&Blds[(d * 32 + 16 + lr) * 40 + kg * 8];
        #pragma unroll
        for (int mt = 0; mt < 2; ++mt) {
          int ryy = wid * 2 + mt + 1 + dy;
          int rxx = lr + 1 + dx;
          bf16x8 af = *(const bf16x8*)&Alds[(ryy * 18 + rxx) * 40 + kg * 8];
          acc[mt][0] = __builtin_amdgcn_mfma_f32_16x16x32_bf16(af, b0, acc[mt][0], 0, 0, 0);
          acc[mt][1] = __builtin_amdgcn_mfma_f32_16x16x32_bf16(af, b1, acc[mt][1], 0, 0, 0);
        }
      }
    }
  }

  // epilogue: D col = lane&15 -> o, D row = kg*4+j -> pixel x
  int x0 = tx0 + kg * 4;
  int f = th >> 2;
  #pragma unroll
  for (int mt = 0; mt < 2; ++mt) {
    int y = ty0 + wid * 2 + mt;
    #pragma unroll
    for (int nt = 0; nt < 2; ++nt) {
      int o = g * 32 + nt * 16 + lr;
      float bias = pb[o];
      float4 res = make_float4(acc[mt][nt][0] + bias, acc[mt][nt][1] + bias,
                               acc[mt][nt][2] + bias, acc[mt][nt][3] + bias);
      *(float4*)&outp[(size_t)(f * 128 + o) * 9216 + y * 96 + x0] = res;
    }
  }
}

// ---------------------------------------------------------------------------
extern "C" void kernel_launch(void* const* d_in, const int* in_sizes, int n_in,
                              void* d_out, int out_size, void* d_ws, size_t ws_size,
                              hipStream_t stream) {
  const float* vid = (const float*)d_in[0];
  const float* lnw = (const float*)d_in[1];
  const float* lnb = (const float*)d_in[2];
  const float* wq  = (const float*)d_in[3];
  const float* bq  = (const float*)d_in[4];
  const float* wk  = (const float*)d_in[5];
  const float* bk  = (const float*)d_in[6];
  const float* wv_ = (const float*)d_in[7];
  const float* bv  = (const float*)d_in[8];
  const float* pw  = (const float*)d_in[9];
  const float* pb  = (const float*)d_in[10];
  float* outp = (float*)d_out;

  const size_t SZ_T  = (size_t)16 * 9216 * 32 * 4;     // q/k fp32 each
  const size_t SZ_TB = (size_t)16 * 9216 * 32 * 2;     // v bf16
  const size_t SZ_W  = (size_t)16 * 9216 * 16 * 4;     // wgt / ind
  const size_t SZ_WT = 128 * 384 * 4;
  const size_t SZ_PW = (size_t)4 * 16 * 9 * 32 * 32 * 2;
  const size_t SZ_MU = (size_t)4 * 9216 * 4;

  char* p = (char*)d_ws;
  float* qb = (float*)p;        p += SZ_T;
  float* kb = (float*)p;        p += SZ_T;
  __bf16* vbbf = (__bf16*)p;    p += SZ_TB;
  float* wgtb = (float*)p;      p += SZ_W;
  int*   indb = (int*)p;        p += SZ_W;
  float* Wt = (float*)p;        p += SZ_WT;
  __bf16* pwt = (__bf16*)p;     p += SZ_PW;
  float* mu = (float*)p;        p += SZ_MU;
  float* rs = (float*)p;

  prep_kernel<<<2496, 256, 0, stream>>>(wq, wk, wv_, pw, Wt, pwt);
  ln_stats_kernel<<<dim3(144, 4), 64, 0, stream>>>(vid, mu, rs);
  qkv_gemm_kernel<<<dim3(3, 288), 512, 0, stream>>>(vid, mu, rs, lnw, lnb, Wt, bq, bk, bv,
                                                    qb, kb, vbbf);
  search_kernel<<<dim3(64, 16), 256, 0, stream>>>(qb, kb, wgtb, indb);
  proj_kernel<<<576, 512, 0, stream>>>(vbbf, wgtb, indb, pwt, pb, outp);
}

// Round 5
// 238.643 us; speedup vs baseline: 1.3994x; 1.0059x over previous
//
#include <hip/hip_runtime.h>

// NonLocalAttentionStack on MI355X.
// Dims: B=1, T=4, C=128, H=W=96, NHEADS=4 (c=32/head), WS=7 (49 cands), PS=3, K=16.
// Pipeline: prep -> ln_stats -> QKV (fp32 GEMM; v output bf16) ->
//           search+topk+softmax (fp32, XOR-swizzled k staging) ->
//           fused gather+implicit-conv MFMA GEMM (XCD-swizzled, T14 prefetch).

typedef float  f32x4  __attribute__((ext_vector_type(4)));
typedef __bf16 bf16x8 __attribute__((ext_vector_type(8)));
typedef __bf16 bf16x4 __attribute__((ext_vector_type(4)));

// ---------------------------------------------------------------------------
// prep: Wt[c][o=384] = {wq|wk|wv}[o][c];  pwt[g][kd][d=9][o=32][i=32] bf16
// ---------------------------------------------------------------------------
__global__ __launch_bounds__(256) void prep_kernel(
    const float* __restrict__ wq, const float* __restrict__ wk, const float* __restrict__ wv,
    const float* __restrict__ pw, float* __restrict__ Wt, __bf16* __restrict__ pwt) {
  int idx = blockIdx.x * 256 + threadIdx.x;
  const int NPW = 4 * 16 * 9 * 32 * 32;  // 589824
  if (idx < NPW) {
    int i  = idx & 31;
    int ol = (idx >> 5) & 31;
    int d  = (idx >> 10) % 9;
    int r  = (idx >> 10) / 9;   // g*16+kd
    int kd = r & 15;
    int g  = r >> 4;
    int o  = g * 32 + ol;
    pwt[idx] = (__bf16)pw[((o * 32 + i) * 16 + kd) * 9 + d];
  } else {
    int widx = idx - NPW;
    if (widx < 128 * 384) {
      int o = widx % 384;
      int c = widx / 384;
      const float* __restrict__ src = (o < 128) ? wq : (o < 256 ? wk : wv);
      Wt[widx] = src[(o & 127) * 128 + c];
    }
  }
}

// ---------------------------------------------------------------------------
// LN stats: per-pixel mean / rsqrt(var+eps).  grid (144,4) x 64 threads.
// ---------------------------------------------------------------------------
__global__ __launch_bounds__(64) void ln_stats_kernel(
    const float* __restrict__ vid, float* __restrict__ mu, float* __restrict__ rs) {
  int pix = blockIdx.x * 64 + threadIdx.x;
  int f = blockIdx.y;
  const float* __restrict__ vp = vid + (size_t)f * 128 * 9216 + pix;
  float s = 0.f, s2 = 0.f;
  #pragma unroll 8
  for (int c = 0; c < 128; ++c) { float x = vp[(size_t)c * 9216]; s += x; s2 += x * x; }
  float m_ = s * (1.f / 128.f);
  float v_ = fmaxf(s2 * (1.f / 128.f) - m_ * m_, 0.f);
  mu[f * 9216 + pix] = m_;
  rs[f * 9216 + pix] = rsqrtf(v_ + 1e-6f);
}

// ---------------------------------------------------------------------------
// QKV GEMM: 128x128 tile, K=128 in 4x32 chunks, 512 threads (8 waves),
// register double-buffered staging.  grid (3, 288); blockIdx.x selects q/k/v.
// q,k: fp32 [t*4+head][pix][c32].  v: bf16 same layout.
// ---------------------------------------------------------------------------
__global__ __launch_bounds__(512) void qkv_gemm_kernel(
    const float* __restrict__ vid, const float* __restrict__ mu, const float* __restrict__ rs,
    const float* __restrict__ lnw, const float* __restrict__ lnb,
    const float* __restrict__ Wt, const float* __restrict__ bq, const float* __restrict__ bk,
    const float* __restrict__ bv, float* __restrict__ qb, float* __restrict__ kb,
    __bf16* __restrict__ vbbf) {
  __shared__ __align__(16) float Xs[32][128];
  __shared__ __align__(16) float Ws[32][128];
  __shared__ float muL[128], rsL[128], lwS[128], lbS[128];
  int tid = threadIdx.x;
  int mt = blockIdx.y;
  int N0 = blockIdx.x * 128;
  int f  = mt / 72;
  int pf = (mt % 72) * 128;

  if (tid < 128) {
    muL[tid] = mu[f * 9216 + pf + tid];
    rsL[tid] = rs[f * 9216 + pf + tid];
  } else if (tid < 256) {
    int t2 = tid - 128;
    lwS[t2] = lnw[t2];
    lbS[t2] = lnb[t2];
  }

  int tx = tid & 15, ty = tid >> 4;   // ty 0..31
  int m0 = ty * 4;
  int sm = tid & 127;                  // staging column
  int sk = tid >> 7;                   // staging row base (0..3)
  float acc[4][8];
  #pragma unroll
  for (int a = 0; a < 4; ++a)
    #pragma unroll
    for (int b = 0; b < 8; ++b) acc[a][b] = 0.f;

  const size_t vbase = (size_t)f * 128 * 9216 + pf;
  float xr[8], wr[8];

  #pragma unroll
  for (int it = 0; it < 8; ++it) {
    int kk = sk + 4 * it;
    xr[it] = vid[vbase + (size_t)kk * 9216 + sm];
    wr[it] = Wt[(size_t)kk * 384 + N0 + sm];
  }
  __syncthreads();
  #pragma unroll
  for (int it = 0; it < 8; ++it) {
    int kk = sk + 4 * it;
    Xs[kk][sm] = (xr[it] - muL[sm]) * rsL[sm] * lwS[kk] + lbS[kk];
    Ws[kk][sm] = wr[it];
  }
  __syncthreads();

  for (int kc = 0; kc < 4; ++kc) {
    if (kc < 3) {
      #pragma unroll
      for (int it = 0; it < 8; ++it) {
        int kk = sk + 4 * it;
        int c = (kc + 1) * 32 + kk;
        xr[it] = vid[vbase + (size_t)c * 9216 + sm];
        wr[it] = Wt[(size_t)c * 384 + N0 + sm];
      }
    }
    #pragma unroll 4
    for (int kk = 0; kk < 32; ++kk) {
      float xa[4], wa[8];
      *(float4*)&xa[0] = *(const float4*)&Xs[kk][m0];
      *(float4*)&wa[0] = *(const float4*)&Ws[kk][tx * 4];
      *(float4*)&wa[4] = *(const float4*)&Ws[kk][64 + tx * 4];
      #pragma unroll
      for (int a = 0; a < 4; ++a)
        #pragma unroll
        for (int b = 0; b < 8; ++b)
          acc[a][b] = fmaf(xa[a], wa[b], acc[a][b]);
    }
    if (kc < 3) {
      __syncthreads();
      #pragma unroll
      for (int it = 0; it < 8; ++it) {
        int kk = sk + 4 * it;
        int c = (kc + 1) * 32 + kk;
        Xs[kk][sm] = (xr[it] - muL[sm]) * rsL[sm] * lwS[c] + lbS[c];
        Ws[kk][sm] = wr[it];
      }
      __syncthreads();
    }
  }

  int sel = blockIdx.x;
  int nlo = tx * 4, nhi = 64 + tx * 4;
  int hlo = nlo >> 5, clo = nlo & 31;
  int hhi = nhi >> 5, chi = nhi & 31;
  const float* __restrict__ bias = (sel == 0) ? bq : (sel == 1 ? bk : bv);
  float4 blo = make_float4(bias[nlo], bias[nlo + 1], bias[nlo + 2], bias[nlo + 3]);
  float4 bhi = make_float4(bias[nhi], bias[nhi + 1], bias[nhi + 2], bias[nhi + 3]);
  size_t base_lo = (size_t)(f * 4 + hlo) * 9216 * 32 + clo;
  size_t base_hi = (size_t)(f * 4 + hhi) * 9216 * 32 + chi;
  if (sel < 2) {
    float* __restrict__ dst = (sel == 0) ? qb : kb;
    #pragma unroll
    for (int a = 0; a < 4; ++a) {
      size_t poff = (size_t)(pf + m0 + a) * 32;
      *(float4*)&dst[base_lo + poff] = make_float4(acc[a][0] + blo.x, acc[a][1] + blo.y,
                                                   acc[a][2] + blo.z, acc[a][3] + blo.w);
      *(float4*)&dst[base_hi + poff] = make_float4(acc[a][4] + bhi.x, acc[a][5] + bhi.y,
                                                   acc[a][6] + bhi.z, acc[a][7] + bhi.w);
    }
  } else {
    #pragma unroll
    for (int a = 0; a < 4; ++a) {
      size_t poff = (size_t)(pf + m0 + a) * 32;
      bf16x4 lo4, hi4;
      lo4[0] = (__bf16)(acc[a][0] + blo.x); lo4[1] = (__bf16)(acc[a][1] + blo.y);
      lo4[2] = (__bf16)(acc[a][2] + blo.z); lo4[3] = (__bf16)(acc[a][3] + blo.w);
      hi4[0] = (__bf16)(acc[a][4] + bhi.x); hi4[1] = (__bf16)(acc[a][5] + bhi.y);
      hi4[2] = (__bf16)(acc[a][6] + bhi.z); hi4[3] = (__bf16)(acc[a][7] + bhi.w);
      *(bf16x4*)&vbbf[base_lo + poff] = lo4;
      *(bf16x4*)&vbbf[base_hi + poff] = hi4;
    }
  }
}

// ---------------------------------------------------------------------------
// search + topk + softmax.  12x12 pixel tile per block, one (t,head).
// k-region 20x20x32 fp32 staged in LDS, XOR-swizzled (quad c4 of pixel p at
// slot c4^(p&7), stride 32 -> conflict-free writes, ~free reads, 51.2 KB ->
// 3 blocks/CU).  slds double-buffered -> one barrier per offset.
// grid (64, 16), 256 threads (196 active for s/topk).
// ---------------------------------------------------------------------------
__global__ __launch_bounds__(256) void search_kernel(
    const float* __restrict__ qb, const float* __restrict__ kb,
    float* __restrict__ wgtb, int* __restrict__ indb) {
  __shared__ __align__(16) float klds[400 * 32];
  __shared__ float slds[2][200];
  int tid = threadIdx.x;
  int th = blockIdx.y;
  int tile = blockIdx.x;
  int ty0 = (tile >> 3) * 12, tx0 = (tile & 7) * 12;
  const float* __restrict__ kbase = kb + (size_t)th * 9216 * 32;

  for (int i = tid; i < 400 * 8; i += 256) {
    int pix = i >> 3, c4 = i & 7;
    int ry = pix / 20, rx = pix % 20;
    int gy = ty0 - 4 + ry, gx = tx0 - 4 + rx;
    float4 val = make_float4(0.f, 0.f, 0.f, 0.f);
    if ((unsigned)gy < 96u && (unsigned)gx < 96u)
      val = *(const float4*)&kbase[(size_t)(gy * 96 + gx) * 32 + c4 * 4];
    *(float4*)&klds[pix * 32 + ((c4 ^ (pix & 7)) << 2)] = val;
  }

  int sy = tid / 14, sx = tid % 14;
  bool active = tid < 196;
  int gy = ty0 - 1 + sy, gx = tx0 - 1 + sx;
  bool qok = active && (unsigned)gy < 96u && (unsigned)gx < 96u;
  float4 qv[8];
  #pragma unroll
  for (int j = 0; j < 8; ++j) qv[j] = make_float4(0.f, 0.f, 0.f, 0.f);
  if (qok) {
    const float* __restrict__ qp = qb + ((size_t)th * 9216 + gy * 96 + gx) * 32;
    #pragma unroll
    for (int j = 0; j < 8; ++j) qv[j] = *(const float4*)&qp[j * 4];
  }
  bool inner = active && sy >= 1 && sy <= 12 && sx >= 1 && sx <= 12;
  int py = ty0 + sy - 1, px = tx0 + sx - 1;

  float tv[16]; int tix[16];
  #pragma unroll
  for (int j = 0; j < 16; ++j) { tv[j] = -3.0e38f; tix[j] = 0; }
  __syncthreads();

  for (int oi = 0; oi < 49; ++oi) {
    int dy = oi / 7, dx = oi % 7;
    if (active) {
      int p = (sy + dy) * 20 + (sx + dx);
      const float* __restrict__ kp = &klds[p * 32];
      int sw = p & 7;
      float sdot = 0.f;
      #pragma unroll
      for (int j = 0; j < 8; ++j) {
        float4 kv = *(const float4*)&kp[(j ^ sw) << 2];
        sdot += qv[j].x * kv.x + qv[j].y * kv.y + qv[j].z * kv.z + qv[j].w * kv.w;
      }
      slds[oi & 1][tid] = sdot;
    }
    __syncthreads();
    // single barrier per offset is race-free with the double buffer:
    // R(b_{i-1}) precedes W(b_i) in program order, which precedes S_i,
    // which precedes any thread's W(b_{i+1}).
    if (inner) {
      const float* __restrict__ sb = slds[oi & 1];
      float sc = 0.f;
      #pragma unroll
      for (int a = 0; a < 3; ++a)
        #pragma unroll
        for (int b = 0; b < 3; ++b)
          sc += sb[(sy - 1 + a) * 14 + (sx - 1 + b)];
      float cv = sc; int ci = oi; bool ins = false;
      #pragma unroll
      for (int j = 0; j < 16; ++j) {
        bool sw2 = ins || (cv > tv[j]);
        float pv = tv[j]; int pi = tix[j];
        tv[j]  = sw2 ? cv : pv;
        tix[j] = sw2 ? ci : pi;
        cv = sw2 ? pv : cv;
        ci = sw2 ? pi : ci;
        ins = sw2;
      }
    }
  }

  if (inner) {
    float mx = tv[0];
    float e[16], ssum = 0.f;
    #pragma unroll
    for (int j = 0; j < 16; ++j) { e[j] = __expf(tv[j] - mx); ssum += e[j]; }
    float inv = 1.f / ssum;
    size_t base = ((size_t)th * 9216 + py * 96 + px) * 16;
    #pragma unroll
    for (int j = 0; j < 4; ++j) {
      *(float4*)&wgtb[base + j * 4] =
          make_float4(e[j*4] * inv, e[j*4+1] * inv, e[j*4+2] * inv, e[j*4+3] * inv);
      *(int4*)&indb[base + j * 4] = make_int4(tix[j*4], tix[j*4+1], tix[j*4+2], tix[j*4+3]);
    }
  }
}

// ---------------------------------------------------------------------------
// fused gather + implicit-conv GEMM, XCD-swizzled, T14 reg-prefetch.
// grid 576 (1D), 512 threads (8 waves).  16x16 px tile, 18x18 halo.
// ---------------------------------------------------------------------------
__global__ __launch_bounds__(512) void proj_kernel(
    const __bf16* __restrict__ vb, const float* __restrict__ wgtb, const int* __restrict__ indb,
    const __bf16* __restrict__ pwt, const float* __restrict__ pb, float* __restrict__ outp) {
  __shared__ __align__(16) __bf16 Alds[324 * 40];
  __shared__ __align__(16) __bf16 Blds[288 * 40];
  int tid = threadIdx.x;
  int bid = blockIdx.x;
  int wg = (bid & 7) * 72 + (bid >> 3);   // XCD-contiguous remap (576 = 8*72)
  int th = wg / 36;                        // f*4+g
  int tile = wg % 36;
  int g = th & 3;
  int ty0 = (tile / 6) * 16, tx0 = (tile % 6) * 16;
  int lane = tid & 63, wid = tid >> 6;     // wid 0..7
  int kg = lane >> 4, lr = lane & 15;

  bool gact = tid < 324;
  int ry = tid / 18, rx = tid % 18;
  int gy = ty0 - 1 + ry, gx = tx0 - 1 + rx;
  bool inb = gact && (unsigned)gy < 96u && (unsigned)gx < 96u;
  const __bf16* __restrict__ vbase = vb + (size_t)th * 9216 * 32;
  size_t pxoff = inb ? (size_t)(gy * 96 + gx) : 0;
  const int*   __restrict__ ibase = indb + ((size_t)th * 9216 + pxoff) * 16;
  const float* __restrict__ wbase = wgtb + ((size_t)th * 9216 + pxoff) * 16;

  f32x4 acc[2][2];
  acc[0][0] = (f32x4)(0.0f); acc[0][1] = (f32x4)(0.0f);
  acc[1][0] = (f32x4)(0.0f); acc[1][1] = (f32x4)(0.0f);

  int4 iw_i = make_int4(0, 0, 0, 0);
  float4 iw_w = make_float4(0.f, 0.f, 0.f, 0.f);
  int4 vr[4];
  vr[0] = vr[1] = vr[2] = vr[3] = make_int4(0, 0, 0, 0);
  float wcur = 0.f;

  if (inb) {
    iw_i = *(const int4*)&ibase[0];
    iw_w = *(const float4*)&wbase[0];
    int ind0 = iw_i.x;
    int ny = gy + ind0 / 7 - 3, nx = gx + ind0 % 7 - 3;
    if ((unsigned)ny < 96u && (unsigned)nx < 96u) {
      const int4* __restrict__ vp = (const int4*)(vbase + (size_t)(ny * 96 + nx) * 32);
      vr[0] = vp[0]; vr[1] = vp[1]; vr[2] = vp[2]; vr[3] = vp[3];
    }
    wcur = iw_w.x;
  }

  for (int kdb = 0; kdb < 4; ++kdb) {
    #pragma unroll
    for (int kb = 0; kb < 4; ++kb) {
      int kd = kdb * 4 + kb;
      __syncthreads();
      if (gact) {
        __bf16 tmp[32];
        #pragma unroll
        for (int wv = 0; wv < 4; ++wv) {
          unsigned uu[4] = {(unsigned)vr[wv].x, (unsigned)vr[wv].y,
                            (unsigned)vr[wv].z, (unsigned)vr[wv].w};
          #pragma unroll
          for (int j2 = 0; j2 < 4; ++j2) {
            float lo = __uint_as_float(uu[j2] << 16);
            float hi = __uint_as_float(uu[j2] & 0xffff0000u);
            tmp[wv * 8 + j2 * 2]     = (__bf16)(lo * wcur);
            tmp[wv * 8 + j2 * 2 + 1] = (__bf16)(hi * wcur);
          }
        }
        __bf16* dst = &Alds[tid * 40];
        *(int4*)&dst[0]  = *(const int4*)&tmp[0];
        *(int4*)&dst[8]  = *(const int4*)&tmp[8];
        *(int4*)&dst[16] = *(const int4*)&tmp[16];
        *(int4*)&dst[24] = *(const int4*)&tmp[24];
      }
      {
        const __bf16* __restrict__ bsrc = pwt + (size_t)(g * 16 + kd) * 9216;
        #pragma unroll
        for (int itb = 0; itb < 3; ++itb) {
          int i = itb * 512 + tid;
          if (i < 1152) {
            int row = i >> 2, c = i & 3;
            *(int4*)&Blds[row * 40 + c * 8] = *(const int4*)&bsrc[row * 32 + c * 8];
          }
        }
      }
      __syncthreads();
      if (kd < 15) {
        int indn; float wn;
        if (kb == 3) {
          if (inb) {
            iw_i = *(const int4*)&ibase[kd + 1];
            iw_w = *(const float4*)&wbase[kd + 1];
          }
          indn = iw_i.x; wn = iw_w.x;
        } else {
          indn = (kb == 0) ? iw_i.y : (kb == 1) ? iw_i.z : iw_i.w;
          wn   = (kb == 0) ? iw_w.y : (kb == 1) ? iw_w.z : iw_w.w;
        }
        vr[0] = vr[1] = vr[2] = vr[3] = make_int4(0, 0, 0, 0);
        if (inb) {
          int ny = gy + indn / 7 - 3, nx = gx + indn % 7 - 3;
          if ((unsigned)ny < 96u && (unsigned)nx < 96u) {
            const int4* __restrict__ vp = (const int4*)(vbase + (size_t)(ny * 96 + nx) * 32);
            vr[0] = vp[0]; vr[1] = vp[1]; vr[2] = vp[2]; vr[3] = vp[3];
          }
        }
        wcur = wn;
      }
      #pragma unroll
      for (int d = 0; d < 9; ++d) {
        int dy = d / 3 - 1, dx = d % 3 - 1;
        bf16x8 b0 = *(const bf16x8*)&Blds[(d * 32 + lr) * 40 + kg * 8];
        bf16x8 b1 = *(const bf16x8*)&Blds[(d * 32 + 16 + lr) * 40 + kg * 8];
        #pragma unroll
        for (int mt = 0; mt < 2; ++mt) {
          int ryy = wid * 2 + mt + 1 + dy;
          int rxx = lr + 1 + dx;
          bf16x8 af = *(const bf16x8*)&Alds[(ryy * 18 + rxx) * 40 + kg * 8];
          acc[mt][0] = __builtin_amdgcn_mfma_f32_16x16x32_bf16(af, b0, acc[mt][0], 0, 0, 0);
          acc[mt][1] = __builtin_amdgcn_mfma_f32_16x16x32_bf16(af, b1, acc[mt][1], 0, 0, 0);
        }
      }
    }
  }

  int x0 = tx0 + kg * 4;
  int f = th >> 2;
  #pragma unroll
  for (int mt = 0; mt < 2; ++mt) {
    int y = ty0 + wid * 2 + mt;
    #pragma unroll
    for (int nt = 0; nt < 2; ++nt) {
      int o = g * 32 + nt * 16 + lr;
      float bias = pb[o];
      float4 res = make_float4(acc[mt][nt][0] + bias, acc[mt][nt][1] + bias,
                               acc[mt][nt][2] + bias, acc[mt][nt][3] + bias);
      *(float4*)&outp[(size_t)(f * 128 + o) * 9216 + y * 96 + x0] = res;
    }
  }
}

// ---------------------------------------------------------------------------
extern "C" void kernel_launch(void* const* d_in, const int* in_sizes, int n_in,
                              void* d_out, int out_size, void* d_ws, size_t ws_size,
                              hipStream_t stream) {
  const float* vid = (const float*)d_in[0];
  const float* lnw = (const float*)d_in[1];
  const float* lnb = (const float*)d_in[2];
  const float* wq  = (const float*)d_in[3];
  const float* bq  = (const float*)d_in[4];
  const float* wk  = (const float*)d_in[5];
  const float* bk  = (const float*)d_in[6];
  const float* wv_ = (const float*)d_in[7];
  const float* bv  = (const float*)d_in[8];
  const float* pw  = (const float*)d_in[9];
  const float* pb  = (const float*)d_in[10];
  float* outp = (float*)d_out;

  const size_t SZ_T  = (size_t)16 * 9216 * 32 * 4;     // q/k fp32 each
  const size_t SZ_TB = (size_t)16 * 9216 * 32 * 2;     // v bf16
  const size_t SZ_W  = (size_t)16 * 9216 * 16 * 4;     // wgt / ind
  const size_t SZ_WT = 128 * 384 * 4;
  const size_t SZ_PW = (size_t)4 * 16 * 9 * 32 * 32 * 2;
  const size_t SZ_MU = (size_t)4 * 9216 * 4;

  char* p = (char*)d_ws;
  float* qb = (float*)p;        p += SZ_T;
  float* kb = (float*)p;        p += SZ_T;
  __bf16* vbbf = (__bf16*)p;    p += SZ_TB;
  float* wgtb = (float*)p;      p += SZ_W;
  int*   indb = (int*)p;        p += SZ_W;
  float* Wt = (float*)p;        p += SZ_WT;
  __bf16* pwt = (__bf16*)p;     p += SZ_PW;
  float* mu = (float*)p;        p += SZ_MU;
  float* rs = (float*)p;

  prep_kernel<<<2496, 256, 0, stream>>>(wq, wk, wv_, pw, Wt, pwt);
  ln_stats_kernel<<<dim3(144, 4), 64, 0, stream>>>(vid, mu, rs);
  qkv_gemm_kernel<<<dim3(3, 288), 512, 0, stream>>>(vid, mu, rs, lnw, lnb, Wt, bq, bk, bv,
                                                    qb, kb, vbbf);
  search_kernel<<<dim3(64, 16), 256, 0, stream>>>(qb, kb, wgtb, indb);
  proj_kernel<<<576, 512, 0, stream>>>(vbbf, wgtb, indb, pwt, pb, outp);
}

// Round 6
// 229.473 us; speedup vs baseline: 1.4553x; 1.0400x over previous
//
#include <hip/hip_runtime.h>

// NonLocalAttentionStack on MI355X.
// Dims: B=1, T=4, C=128, H=W=96, NHEADS=4 (c=32/head), WS=7 (49 cands), PS=3, K=16.
// Pipeline: prep -> ln_stats -> QKV (fp32 GEMM; v output bf16) ->
//           search+topk+softmax (fp32, 16x16 tile, rolling k-band, DPP box-sum) ->
//           fused gather+implicit-conv MFMA GEMM (XCD-swizzled, T14 prefetch).

typedef float  f32x4  __attribute__((ext_vector_type(4)));
typedef __bf16 bf16x8 __attribute__((ext_vector_type(8)));
typedef __bf16 bf16x4 __attribute__((ext_vector_type(4)));

__device__ __forceinline__ float dpp_shr1(float x) {  // lane L gets lane L-1 (16-lane rows)
  return __int_as_float(__builtin_amdgcn_update_dpp(0, __float_as_int(x), 0x111, 0xf, 0xf, false));
}
__device__ __forceinline__ float dpp_shl1(float x) {  // lane L gets lane L+1
  return __int_as_float(__builtin_amdgcn_update_dpp(0, __float_as_int(x), 0x101, 0xf, 0xf, false));
}

// ---------------------------------------------------------------------------
// prep: Wt[c][o=384] = {wq|wk|wv}[o][c];  pwt[g][kd][d=9][o=32][i=32] bf16
// ---------------------------------------------------------------------------
__global__ __launch_bounds__(256) void prep_kernel(
    const float* __restrict__ wq, const float* __restrict__ wk, const float* __restrict__ wv,
    const float* __restrict__ pw, float* __restrict__ Wt, __bf16* __restrict__ pwt) {
  int idx = blockIdx.x * 256 + threadIdx.x;
  const int NPW = 4 * 16 * 9 * 32 * 32;  // 589824
  if (idx < NPW) {
    int i  = idx & 31;
    int ol = (idx >> 5) & 31;
    int d  = (idx >> 10) % 9;
    int r  = (idx >> 10) / 9;   // g*16+kd
    int kd = r & 15;
    int g  = r >> 4;
    int o  = g * 32 + ol;
    pwt[idx] = (__bf16)pw[((o * 32 + i) * 16 + kd) * 9 + d];
  } else {
    int widx = idx - NPW;
    if (widx < 128 * 384) {
      int o = widx % 384;
      int c = widx / 384;
      const float* __restrict__ src = (o < 128) ? wq : (o < 256 ? wk : wv);
      Wt[widx] = src[(o & 127) * 128 + c];
    }
  }
}

// ---------------------------------------------------------------------------
// LN stats: per-pixel mean / rsqrt(var+eps).  grid (144,4) x 64 threads.
// ---------------------------------------------------------------------------
__global__ __launch_bounds__(64) void ln_stats_kernel(
    const float* __restrict__ vid, float* __restrict__ mu, float* __restrict__ rs) {
  int pix = blockIdx.x * 64 + threadIdx.x;
  int f = blockIdx.y;
  const float* __restrict__ vp = vid + (size_t)f * 128 * 9216 + pix;
  float s = 0.f, s2 = 0.f;
  #pragma unroll 8
  for (int c = 0; c < 128; ++c) { float x = vp[(size_t)c * 9216]; s += x; s2 += x * x; }
  float m_ = s * (1.f / 128.f);
  float v_ = fmaxf(s2 * (1.f / 128.f) - m_ * m_, 0.f);
  mu[f * 9216 + pix] = m_;
  rs[f * 9216 + pix] = rsqrtf(v_ + 1e-6f);
}

// ---------------------------------------------------------------------------
// QKV GEMM: 128x128 tile, K=128 in 4x32 chunks, 512 threads (8 waves),
// register double-buffered staging.  grid (3, 288); blockIdx.x selects q/k/v.
// q,k: fp32 [t*4+head][pix][c32].  v: bf16 same layout.
// ---------------------------------------------------------------------------
__global__ __launch_bounds__(512) void qkv_gemm_kernel(
    const float* __restrict__ vid, const float* __restrict__ mu, const float* __restrict__ rs,
    const float* __restrict__ lnw, const float* __restrict__ lnb,
    const float* __restrict__ Wt, const float* __restrict__ bq, const float* __restrict__ bk,
    const float* __restrict__ bv, float* __restrict__ qb, float* __restrict__ kb,
    __bf16* __restrict__ vbbf) {
  __shared__ __align__(16) float Xs[32][128];
  __shared__ __align__(16) float Ws[32][128];
  __shared__ float muL[128], rsL[128], lwS[128], lbS[128];
  int tid = threadIdx.x;
  int mt = blockIdx.y;
  int N0 = blockIdx.x * 128;
  int f  = mt / 72;
  int pf = (mt % 72) * 128;

  if (tid < 128) {
    muL[tid] = mu[f * 9216 + pf + tid];
    rsL[tid] = rs[f * 9216 + pf + tid];
  } else if (tid < 256) {
    int t2 = tid - 128;
    lwS[t2] = lnw[t2];
    lbS[t2] = lnb[t2];
  }

  int tx = tid & 15, ty = tid >> 4;   // ty 0..31
  int m0 = ty * 4;
  int sm = tid & 127;                  // staging column
  int sk = tid >> 7;                   // staging row base (0..3)
  float acc[4][8];
  #pragma unroll
  for (int a = 0; a < 4; ++a)
    #pragma unroll
    for (int b = 0; b < 8; ++b) acc[a][b] = 0.f;

  const size_t vbase = (size_t)f * 128 * 9216 + pf;
  float xr[8], wr[8];

  #pragma unroll
  for (int it = 0; it < 8; ++it) {
    int kk = sk + 4 * it;
    xr[it] = vid[vbase + (size_t)kk * 9216 + sm];
    wr[it] = Wt[(size_t)kk * 384 + N0 + sm];
  }
  __syncthreads();
  #pragma unroll
  for (int it = 0; it < 8; ++it) {
    int kk = sk + 4 * it;
    Xs[kk][sm] = (xr[it] - muL[sm]) * rsL[sm] * lwS[kk] + lbS[kk];
    Ws[kk][sm] = wr[it];
  }
  __syncthreads();

  for (int kc = 0; kc < 4; ++kc) {
    if (kc < 3) {
      #pragma unroll
      for (int it = 0; it < 8; ++it) {
        int kk = sk + 4 * it;
        int c = (kc + 1) * 32 + kk;
        xr[it] = vid[vbase + (size_t)c * 9216 + sm];
        wr[it] = Wt[(size_t)c * 384 + N0 + sm];
      }
    }
    #pragma unroll 4
    for (int kk = 0; kk < 32; ++kk) {
      float xa[4], wa[8];
      *(float4*)&xa[0] = *(const float4*)&Xs[kk][m0];
      *(float4*)&wa[0] = *(const float4*)&Ws[kk][tx * 4];
      *(float4*)&wa[4] = *(const float4*)&Ws[kk][64 + tx * 4];
      #pragma unroll
      for (int a = 0; a < 4; ++a)
        #pragma unroll
        for (int b = 0; b < 8; ++b)
          acc[a][b] = fmaf(xa[a], wa[b], acc[a][b]);
    }
    if (kc < 3) {
      __syncthreads();
      #pragma unroll
      for (int it = 0; it < 8; ++it) {
        int kk = sk + 4 * it;
        int c = (kc + 1) * 32 + kk;
        Xs[kk][sm] = (xr[it] - muL[sm]) * rsL[sm] * lwS[c] + lbS[c];
        Ws[kk][sm] = wr[it];
      }
      __syncthreads();
    }
  }

  int sel = blockIdx.x;
  int nlo = tx * 4, nhi = 64 + tx * 4;
  int hlo = nlo >> 5, clo = nlo & 31;
  int hhi = nhi >> 5, chi = nhi & 31;
  const float* __restrict__ bias = (sel == 0) ? bq : (sel == 1 ? bk : bv);
  float4 blo = make_float4(bias[nlo], bias[nlo + 1], bias[nlo + 2], bias[nlo + 3]);
  float4 bhi = make_float4(bias[nhi], bias[nhi + 1], bias[nhi + 2], bias[nhi + 3]);
  size_t base_lo = (size_t)(f * 4 + hlo) * 9216 * 32 + clo;
  size_t base_hi = (size_t)(f * 4 + hhi) * 9216 * 32 + chi;
  if (sel < 2) {
    float* __restrict__ dst = (sel == 0) ? qb : kb;
    #pragma unroll
    for (int a = 0; a < 4; ++a) {
      size_t poff = (size_t)(pf + m0 + a) * 32;
      *(float4*)&dst[base_lo + poff] = make_float4(acc[a][0] + blo.x, acc[a][1] + blo.y,
                                                   acc[a][2] + blo.z, acc[a][3] + blo.w);
      *(float4*)&dst[base_hi + poff] = make_float4(acc[a][4] + bhi.x, acc[a][5] + bhi.y,
                                                   acc[a][6] + bhi.z, acc[a][7] + bhi.w);
    }
  } else {
    #pragma unroll
    for (int a = 0; a < 4; ++a) {
      size_t poff = (size_t)(pf + m0 + a) * 32;
      bf16x4 lo4, hi4;
      lo4[0] = (__bf16)(acc[a][0] + blo.x); lo4[1] = (__bf16)(acc[a][1] + blo.y);
      lo4[2] = (__bf16)(acc[a][2] + blo.z); lo4[3] = (__bf16)(acc[a][3] + blo.w);
      hi4[0] = (__bf16)(acc[a][4] + bhi.x); hi4[1] = (__bf16)(acc[a][5] + bhi.y);
      hi4[2] = (__bf16)(acc[a][6] + bhi.z); hi4[3] = (__bf16)(acc[a][7] + bhi.w);
      *(bf16x4*)&vbbf[base_lo + poff] = lo4;
      *(bf16x4*)&vbbf[base_hi + poff] = hi4;
    }
  }
}

// ---------------------------------------------------------------------------
// search + topk + softmax.  16x16 s-region tile (inner 14x14 queries), one
// (t,head) per blockIdx.y.  k staged as rolling 16-row band (slot = row&15),
// 22 cols x 32 ch fp32, quad-XOR swizzle: quad c4 of pixel p at dword
// p*32 + ((c4^(p&7))<<2) -> b128 reads/writes at the 2-lanes-per-bank-group
// floor (quarter-wave == tile row of 16).  Horizontal box-sum via DPP
// (symmetric, so shr/shl direction-proof); vertical via slds (double-buffered,
// one barrier per offset).  Top-16 via max/min compare-exchange cascade
// (strict > keeps jax tie->lower-index semantics).
// grid (49, 16), 256 threads, 3 blocks/CU (47 KB LDS).
// ---------------------------------------------------------------------------
__global__ __launch_bounds__(256, 3) void search_kernel(
    const float* __restrict__ qb, const float* __restrict__ kb,
    float* __restrict__ wgtb, int* __restrict__ indb) {
  __shared__ __align__(16) float klds[16 * 22 * 32];   // 45056 B
  __shared__ float slds[2][256];
  int tid = threadIdx.x;
  int th = blockIdx.y;
  int tile = blockIdx.x;
  int iy0 = (tile / 7) * 14, ix0 = (tile % 7) * 14;
  const float* __restrict__ kbase = kb + (size_t)th * 9216 * 32;

  // initial stage: k-region rows 0..15 (slot == row), 16*22*8 = 2816 quads
  #pragma unroll
  for (int it = 0; it < 11; ++it) {
    int i = it * 256 + tid;
    int r = i / 176, rem = i % 176;
    int col = rem >> 3, c4 = rem & 7;
    int gy = iy0 - 4 + r, gx = ix0 - 4 + col;
    float4 val = make_float4(0.f, 0.f, 0.f, 0.f);
    if ((unsigned)gy < 96u && (unsigned)gx < 96u)
      val = *(const float4*)&kbase[(size_t)(gy * 96 + gx) * 32 + c4 * 4];
    int p = r * 22 + col;
    *(float4*)&klds[p * 32 + ((c4 ^ (p & 7)) << 2)] = val;
  }

  int sy = tid >> 4, sx = tid & 15;
  int qy = iy0 - 1 + sy, qx = ix0 - 1 + sx;
  bool qok = (unsigned)qy < 96u && (unsigned)qx < 96u;
  float4 qv[8];
  #pragma unroll
  for (int j = 0; j < 8; ++j) qv[j] = make_float4(0.f, 0.f, 0.f, 0.f);
  if (qok) {
    const float* __restrict__ qp = qb + ((size_t)th * 9216 + qy * 96 + qx) * 32;
    #pragma unroll
    for (int j = 0; j < 8; ++j) qv[j] = *(const float4*)&qp[j * 4];
  }
  bool inner = (sy >= 1) && (sy <= 14) && (sx >= 1) && (sx <= 14) && qok;

  float tv[16]; int tix[16];
  #pragma unroll
  for (int j = 0; j < 16; ++j) { tv[j] = -3.0e38f; tix[j] = 0; }
  __syncthreads();

  #pragma unroll 1
  for (int dy = 0; dy < 7; ++dy) {
    if (dy > 0) {
      // stage k-region row dy+15 into slot (dy+15)&15 == dy-1
      // (safe: every thread's last read of slot dy-1 preceded the previous
      //  offset's barrier, which precedes this write in program order)
      if (tid < 176) {
        int col = tid >> 3, c4 = tid & 7;
        int r = dy + 15;
        int gy = iy0 - 4 + r, gx = ix0 - 4 + col;
        float4 val = make_float4(0.f, 0.f, 0.f, 0.f);
        if ((unsigned)gy < 96u && (unsigned)gx < 96u)
          val = *(const float4*)&kbase[(size_t)(gy * 96 + gx) * 32 + c4 * 4];
        int p = (r & 15) * 22 + col;
        *(float4*)&klds[p * 32 + ((c4 ^ (p & 7)) << 2)] = val;
      }
      __syncthreads();
    }
    #pragma unroll 1
    for (int dx = 0; dx < 7; ++dx) {
      int oi = dy * 7 + dx;
      // pixel dot: s-pixel (sy,sx) vs k pixel (sy+dy, sx+dx) in region coords
      int p = ((sy + dy) & 15) * 22 + (sx + dx);
      const float* __restrict__ kp = &klds[p * 32];
      int sw = p & 7;
      float sdot = 0.f;
      #pragma unroll
      for (int j = 0; j < 8; ++j) {
        float4 kq = *(const float4*)&kp[(j ^ sw) << 2];
        sdot += qv[j].x * kq.x + qv[j].y * kq.y + qv[j].z * kq.z + qv[j].w * kq.w;
      }
      // horizontal 3-sum in-register (row edges wrong but unused)
      float h = sdot + dpp_shr1(sdot) + dpp_shl1(sdot);
      slds[oi & 1][tid] = h;
      __syncthreads();
      if (inner) {
        const float* __restrict__ sb = slds[oi & 1];
        float sc = h + sb[tid - 16] + sb[tid + 16];
        // top-16 insert: max/min compare-exchange cascade
        float cv = sc; int ci = oi;
        #pragma unroll
        for (int j = 0; j < 16; ++j) {
          bool gt = cv > tv[j];
          float mx = fmaxf(tv[j], cv);
          float mn = fminf(tv[j], cv);
          int nt = gt ? ci : tix[j];
          ci = gt ? tix[j] : ci;
          tv[j] = mx; cv = mn; tix[j] = nt;
        }
      }
    }
  }

  if (inner) {
    float mx = tv[0];
    float e[16], ssum = 0.f;
    #pragma unroll
    for (int j = 0; j < 16; ++j) { e[j] = __expf(tv[j] - mx); ssum += e[j]; }
    float inv = 1.f / ssum;
    size_t base = ((size_t)th * 9216 + qy * 96 + qx) * 16;
    #pragma unroll
    for (int j = 0; j < 4; ++j) {
      *(float4*)&wgtb[base + j * 4] =
          make_float4(e[j*4] * inv, e[j*4+1] * inv, e[j*4+2] * inv, e[j*4+3] * inv);
      *(int4*)&indb[base + j * 4] = make_int4(tix[j*4], tix[j*4+1], tix[j*4+2], tix[j*4+3]);
    }
  }
}

// ---------------------------------------------------------------------------
// fused gather + implicit-conv GEMM, XCD-swizzled, T14 reg-prefetch.
// grid 576 (1D), 512 threads (8 waves).  16x16 px tile, 18x18 halo.
// ---------------------------------------------------------------------------
__global__ __launch_bounds__(512) void proj_kernel(
    const __bf16* __restrict__ vb, const float* __restrict__ wgtb, const int* __restrict__ indb,
    const __bf16* __restrict__ pwt, const float* __restrict__ pb, float* __restrict__ outp) {
  __shared__ __align__(16) __bf16 Alds[324 * 40];
  __shared__ __align__(16) __bf16 Blds[288 * 40];
  int tid = threadIdx.x;
  int bid = blockIdx.x;
  int wg = (bid & 7) * 72 + (bid >> 3);   // XCD-contiguous remap (576 = 8*72)
  int th = wg / 36;                        // f*4+g
  int tile = wg % 36;
  int g = th & 3;
  int ty0 = (tile / 6) * 16, tx0 = (tile % 6) * 16;
  int lane = tid & 63, wid = tid >> 6;     // wid 0..7
  int kg = lane >> 4, lr = lane & 15;

  bool gact = tid < 324;
  int ry = tid / 18, rx = tid % 18;
  int gy = ty0 - 1 + ry, gx = tx0 - 1 + rx;
  bool inb = gact && (unsigned)gy < 96u && (unsigned)gx < 96u;
  const __bf16* __restrict__ vbase = vb + (size_t)th * 9216 * 32;
  size_t pxoff = inb ? (size_t)(gy * 96 + gx) : 0;
  const int*   __restrict__ ibase = indb + ((size_t)th * 9216 + pxoff) * 16;
  const float* __restrict__ wbase = wgtb + ((size_t)th * 9216 + pxoff) * 16;

  f32x4 acc[2][2];
  acc[0][0] = (f32x4)(0.0f); acc[0][1] = (f32x4)(0.0f);
  acc[1][0] = (f32x4)(0.0f); acc[1][1] = (f32x4)(0.0f);

  int4 iw_i = make_int4(0, 0, 0, 0);
  float4 iw_w = make_float4(0.f, 0.f, 0.f, 0.f);
  int4 vr[4];
  vr[0] = vr[1] = vr[2] = vr[3] = make_int4(0, 0, 0, 0);
  float wcur = 0.f;

  if (inb) {
    iw_i = *(const int4*)&ibase[0];
    iw_w = *(const float4*)&wbase[0];
    int ind0 = iw_i.x;
    int ny = gy + ind0 / 7 - 3, nx = gx + ind0 % 7 - 3;
    if ((unsigned)ny < 96u && (unsigned)nx < 96u) {
      const int4* __restrict__ vp = (const int4*)(vbase + (size_t)(ny * 96 + nx) * 32);
      vr[0] = vp[0]; vr[1] = vp[1]; vr[2] = vp[2]; vr[3] = vp[3];
    }
    wcur = iw_w.x;
  }

  for (int kdb = 0; kdb < 4; ++kdb) {
    #pragma unroll
    for (int kb = 0; kb < 4; ++kb) {
      int kd = kdb * 4 + kb;
      __syncthreads();
      if (gact) {
        __bf16 tmp[32];
        #pragma unroll
        for (int wv = 0; wv < 4; ++wv) {
          unsigned uu[4] = {(unsigned)vr[wv].x, (unsigned)vr[wv].y,
                            (unsigned)vr[wv].z, (unsigned)vr[wv].w};
          #pragma unroll
          for (int j2 = 0; j2 < 4; ++j2) {
            float lo = __uint_as_float(uu[j2] << 16);
            float hi = __uint_as_float(uu[j2] & 0xffff0000u);
            tmp[wv * 8 + j2 * 2]     = (__bf16)(lo * wcur);
            tmp[wv * 8 + j2 * 2 + 1] = (__bf16)(hi * wcur);
          }
        }
        __bf16* dst = &Alds[tid * 40];
        *(int4*)&dst[0]  = *(const int4*)&tmp[0];
        *(int4*)&dst[8]  = *(const int4*)&tmp[8];
        *(int4*)&dst[16] = *(const int4*)&tmp[16];
        *(int4*)&dst[24] = *(const int4*)&tmp[24];
      }
      {
        const __bf16* __restrict__ bsrc = pwt + (size_t)(g * 16 + kd) * 9216;
        #pragma unroll
        for (int itb = 0; itb < 3; ++itb) {
          int i = itb * 512 + tid;
          if (i < 1152) {
            int row = i >> 2, c = i & 3;
            *(int4*)&Blds[row * 40 + c * 8] = *(const int4*)&bsrc[row * 32 + c * 8];
          }
        }
      }
      __syncthreads();
      if (kd < 15) {
        int indn; float wn;
        if (kb == 3) {
          if (inb) {
            iw_i = *(const int4*)&ibase[kd + 1];
            iw_w = *(const float4*)&wbase[kd + 1];
          }
          indn = iw_i.x; wn = iw_w.x;
        } else {
          indn = (kb == 0) ? iw_i.y : (kb == 1) ? iw_i.z : iw_i.w;
          wn   = (kb == 0) ? iw_w.y : (kb == 1) ? iw_w.z : iw_w.w;
        }
        vr[0] = vr[1] = vr[2] = vr[3] = make_int4(0, 0, 0, 0);
        if (inb) {
          int ny = gy + indn / 7 - 3, nx = gx + indn % 7 - 3;
          if ((unsigned)ny < 96u && (unsigned)nx < 96u) {
            const int4* __restrict__ vp = (const int4*)(vbase + (size_t)(ny * 96 + nx) * 32);
            vr[0] = vp[0]; vr[1] = vp[1]; vr[2] = vp[2]; vr[3] = vp[3];
          }
        }
        wcur = wn;
      }
      #pragma unroll
      for (int d = 0; d < 9; ++d) {
        int dy = d / 3 - 1, dx = d % 3 - 1;
        bf16x8 b0 = *(const bf16x8*)&Blds[(d * 32 + lr) * 40 + kg * 8];
        bf16x8 b1 = *(const bf16x8*)&Blds[(d * 32 + 16 + lr) * 40 + kg * 8];
        #pragma unroll
        for (int mt = 0; mt < 2; ++mt) {
          int ryy = wid * 2 + mt + 1 + dy;
          int rxx = lr + 1 + dx;
          bf16x8 af = *(const bf16x8*)&Alds[(ryy * 18 + rxx) * 40 + kg * 8];
          acc[mt][0] = __builtin_amdgcn_mfma_f32_16x16x32_bf16(af, b0, acc[mt][0], 0, 0, 0);
          acc[mt][1] = __builtin_amdgcn_mfma_f32_16x16x32_bf16(af, b1, acc[mt][1], 0, 0, 0);
        }
      }
    }
  }

  int x0 = tx0 + kg * 4;
  int f = th >> 2;
  #pragma unroll
  for (int mt = 0; mt < 2; ++mt) {
    int y = ty0 + wid * 2 + mt;
    #pragma unroll
    for (int nt = 0; nt < 2; ++nt) {
      int o = g * 32 + nt * 16 + lr;
      float bias = pb[o];
      float4 res = make_float4(acc[mt][nt][0] + bias, acc[mt][nt][1] + bias,
                               acc[mt][nt][2] + bias, acc[mt][nt][3] + bias);
      *(float4*)&outp[(size_t)(f * 128 + o) * 9216 + y * 96 + x0] = res;
    }
  }
}

// ---------------------------------------------------------------------------
extern "C" void kernel_launch(void* const* d_in, const int* in_sizes, int n_in,
                              void* d_out, int out_size, void* d_ws, size_t ws_size,
                              hipStream_t stream) {
  const float* vid = (const float*)d_in[0];
  const float* lnw = (const float*)d_in[1];
  const float* lnb = (const float*)d_in[2];
  const float* wq  = (const float*)d_in[3];
  const float* bq  = (const float*)d_in[4];
  const float* wk  = (const float*)d_in[5];
  const float* bk  = (const float*)d_in[6];
  const float* wv_ = (const float*)d_in[7];
  const float* bv  = (const float*)d_in[8];
  const float* pw  = (const float*)d_in[9];
  const float* pb  = (const float*)d_in[10];
  float* outp = (float*)d_out;

  const size_t SZ_T  = (size_t)16 * 9216 * 32 * 4;     // q/k fp32 each
  const size_t SZ_TB = (size_t)16 * 9216 * 32 * 2;     // v bf16
  const size_t SZ_W  = (size_t)16 * 9216 * 16 * 4;     // wgt / ind
  const size_t SZ_WT = 128 * 384 * 4;
  const size_t SZ_PW = (size_t)4 * 16 * 9 * 32 * 32 * 2;
  const size_t SZ_MU = (size_t)4 * 9216 * 4;

  char* p = (char*)d_ws;
  float* qb = (float*)p;        p += SZ_T;
  float* kb = (float*)p;        p += SZ_T;
  __bf16* vbbf = (__bf16*)p;    p += SZ_TB;
  float* wgtb = (float*)p;      p += SZ_W;
  int*   indb = (int*)p;        p += SZ_W;
  float* Wt = (float*)p;        p += SZ_WT;
  __bf16* pwt = (__bf16*)p;     p += SZ_PW;
  float* mu = (float*)p;        p += SZ_MU;
  float* rs = (float*)p;

  prep_kernel<<<2496, 256, 0, stream>>>(wq, wk, wv_, pw, Wt, pwt);
  ln_stats_kernel<<<dim3(144, 4), 64, 0, stream>>>(vid, mu, rs);
  qkv_gemm_kernel<<<dim3(3, 288), 512, 0, stream>>>(vid, mu, rs, lnw, lnb, Wt, bq, bk, bv,
                                                    qb, kb, vbbf);
  search_kernel<<<dim3(49, 16), 256, 0, stream>>>(qb, kb, wgtb, indb);
  proj_kernel<<<576, 512, 0, stream>>>(vbbf, wgtb, indb, pwt, pb, outp);
}